// Round 6
// baseline (192.330 us; speedup 1.0000x reference)
//
#include <hip/hip_runtime.h>
#include <hip/hip_bf16.h>
#include <math.h>

typedef __attribute__((ext_vector_type(8))) short b16x8;
typedef __attribute__((ext_vector_type(4))) short b16x4;
typedef __attribute__((ext_vector_type(4))) float floatx4;
typedef __attribute__((ext_vector_type(16))) float f32x16;

constexpr int BATCH = 4, CCH = 384, NQ = 4096, NHD = 8, HDIM = 48, NK = 1024;
constexpr float SCALE = 0.14433756729740643f;            // 48^-0.5
constexpr float SCALE_L2E = 0.14433756729740643f * 1.4426950408889634f; // *log2(e)

__device__ inline unsigned short f2bf(float f) {
    unsigned u = __builtin_bit_cast(unsigned, f);
    u += 0x7fffu + ((u >> 16) & 1u);
    return (unsigned short)(u >> 16);
}

__device__ inline unsigned pk2(float lo, float hi) {
    unsigned short a = __builtin_bit_cast(unsigned short, __float2bfloat16(lo));
    unsigned short b = __builtin_bit_cast(unsigned short, __float2bfloat16(hi));
    return ((unsigned)b << 16) | (unsigned)a;
}

// ---------------------------------------------------------------------------
// Weight conversion fp32 -> bf16.  Wk,Wv stacked into WkvB[768][384].
// Wsr reordered to [o][pos*384+c]  (pos = i*2+j) so the conv-GEMM B operand
// becomes 4 contiguous xT row segments per 64-wide k chunk.
// ---------------------------------------------------------------------------
__global__ void cvt_all(const float* __restrict__ Wq, const float* __restrict__ Wk,
                        const float* __restrict__ Wv, const float* __restrict__ Wsr,
                        const float* __restrict__ Wp,
                        short* __restrict__ WqB, short* __restrict__ WkvB,
                        short* __restrict__ WsrB, short* __restrict__ WpB) {
    int job = blockIdx.y;
    if (job == 3) {
        for (int i = blockIdx.x * 256 + threadIdx.x; i < 589824; i += gridDim.x * 256) {
            int o = i / 1536, r = i - o * 1536;
            WsrB[o * 1536 + (r & 3) * 384 + (r >> 2)] = (short)f2bf(Wsr[i]);
        }
        return;
    }
    const float* src; short* dst;
    if (job == 0)      { src = Wq;  dst = WqB; }
    else if (job == 1) { src = Wk;  dst = WkvB; }
    else if (job == 2) { src = Wv;  dst = WkvB + 147456; }
    else               { src = Wp;  dst = WpB; }
    for (int i = blockIdx.x * 256 + threadIdx.x; i < 147456; i += gridDim.x * 256)
        dst[i] = (short)f2bf(src[i]);
}

// ---------------------------------------------------------------------------
// x [B][384][4096] f32  ->  xT [B][4096][384] bf16 (token-major)
// ---------------------------------------------------------------------------
__global__ void t1_kern(const float* __restrict__ x, short* __restrict__ xT) {
    int b = blockIdx.z, s = blockIdx.x * 64 + (threadIdx.x & 63);
    for (int c8 = blockIdx.y * 8 + (threadIdx.x >> 6); c8 < blockIdx.y * 8 + 8; c8 += 4) {
        b16x8 pk;
        #pragma unroll
        for (int e = 0; e < 8; e++)
            pk[e] = (short)f2bf(x[((size_t)b * CCH + c8 * 8 + e) * NQ + s]);
        *(b16x8*)(xT + ((size_t)b * NQ + s) * CCH + c8 * 8) = pk;
    }
}

// ---------------------------------------------------------------------------
// MFMA GEMM: Y[o][s] = sum_k A[o][k] * B[b][s][k];  128x128 tile, BK=64,
// 4 waves each 64x64 (4x4 frags of 16x16x32).  LDS XOR-swizzled.
// CONV: B operand gathered from xT (im2col on the fly, Wsr pos-major layout).
// EPI: 0 = bf16 transposed out Yt[s][o];  1 = +bias;  2 = fused KV (o<384: k
// with pos+scale*log2e -> Yt; o>=384: v -> Y2 padded-head-major);  3 = f32+bias.
// ---------------------------------------------------------------------------
template<int EPI, bool CONV>
__global__ __launch_bounds__(256, 2) void mfma_gemm(
    const short* __restrict__ A, const short* __restrict__ Bm,
    short* __restrict__ Yt, short* __restrict__ Y2, float* __restrict__ Yf,
    const float* __restrict__ bias, const float* __restrict__ relh,
    const float* __restrict__ relw, int Ksz, int S)
{
    __shared__ short At[128 * 64];
    __shared__ short Bt[128 * 64];
    const int b = blockIdx.z, o0 = blockIdx.y * 128, s0 = blockIdx.x * 128;
    const int t = threadIdx.x, wave = t >> 6, lane = t & 63, g = lane >> 4, li = lane & 15;
    const int wr = wave >> 1, wc = wave & 1;
    floatx4 acc[4][4] = {};
    const int row0 = t >> 3, ch = t & 7;
    const int wch = (ch ^ (row0 & 7)) * 8;  // (row0+32it)&7 == row0&7
    const short* Arow = A + (size_t)(o0 + row0) * Ksz + ch * 8;
    const short* Bbase = Bm + (size_t)b * S * Ksz;   // for CONV: == xT b-slab
    const short* Brow = Bbase + (size_t)(s0 + row0) * Ksz + ch * 8;

    for (int k0 = 0; k0 < Ksz; k0 += 64) {
        __syncthreads();
        #pragma unroll
        for (int it = 0; it < 4; it++) {
            int row = row0 + it * 32;
            *(b16x8*)(At + row * 64 + wch) = *(const b16x8*)(Arow + (size_t)it * 32 * Ksz + k0);
            if constexpr (CONV) {
                int ssr = s0 + row;
                int hs = ssr >> 5, wsv = ssr & 31;
                int k = k0 + ch * 8;
                int p = k / 384, coff = k - p * 384;
                const short* src = Bbase
                    + (size_t)((2 * hs + (p >> 1)) * 64 + 2 * wsv + (p & 1)) * 384 + coff;
                *(b16x8*)(Bt + row * 64 + wch) = *(const b16x8*)src;
            } else {
                *(b16x8*)(Bt + row * 64 + wch) = *(const b16x8*)(Brow + (size_t)it * 32 * Ksz + k0);
            }
        }
        __syncthreads();
        #pragma unroll
        for (int kk = 0; kk < 2; kk++) {
            b16x8 af[4], bf[4];
            #pragma unroll
            for (int mi = 0; mi < 4; mi++) {
                int r = wr * 64 + mi * 16 + li;
                af[mi] = *(const b16x8*)(At + r * 64 + (((kk * 4 + g) ^ (r & 7)) * 8));
            }
            #pragma unroll
            for (int nf = 0; nf < 4; nf++) {
                int r = wc * 64 + nf * 16 + li;
                bf[nf] = *(const b16x8*)(Bt + r * 64 + (((kk * 4 + g) ^ (r & 7)) * 8));
            }
            #pragma unroll
            for (int mi = 0; mi < 4; mi++)
                #pragma unroll
                for (int nf = 0; nf < 4; nf++)
                    acc[mi][nf] = __builtin_amdgcn_mfma_f32_16x16x32_bf16(af[mi], bf[nf], acc[mi][nf], 0, 0, 0);
        }
    }

    #pragma unroll
    for (int mi = 0; mi < 4; mi++) {
        #pragma unroll
        for (int nf = 0; nf < 4; nf++) {
            int o = o0 + wr * 64 + mi * 16 + g * 4;
            int s = s0 + wc * 64 + nf * 16 + li;
            if constexpr (EPI == 0 || EPI == 1) {
                b16x4 pk;
                #pragma unroll
                for (int j = 0; j < 4; j++) {
                    float v = acc[mi][nf][j];
                    if constexpr (EPI == 1) v += bias[o + j];
                    pk[j] = (short)f2bf(v);
                }
                *(b16x4*)(Yt + ((size_t)b * S + s) * CCH + o) = pk;
            } else if constexpr (EPI == 2) {
                if (o0 < 384) {
                    // pos[m] = rel_h[o][m & 31] + rel_w[o][m >> 5]
                    int hs = s >> 5, wsv = s & 31;
                    b16x4 pk;
                    #pragma unroll
                    for (int j = 0; j < 4; j++)
                        pk[j] = (short)f2bf((acc[mi][nf][j] + relh[(o + j) * 32 + wsv]
                                             + relw[(o + j) * 32 + hs]) * SCALE_L2E);
                    *(b16x4*)(Yt + ((size_t)b * S + s) * CCH + o) = pk;
                } else {
                    #pragma unroll
                    for (int j = 0; j < 4; j++) {
                        int cj = o - 384 + j;
                        int head = cj / 48, d = cj - head * 48;
                        Y2[((size_t)b * (NHD * 64) + head * 64 + d) * NK + s] = (short)f2bf(acc[mi][nf][j]);
                    }
                }
            } else {
                #pragma unroll
                for (int j = 0; j < 4; j++)
                    Yf[((size_t)b * CCH + o + j) * (size_t)S + s] = acc[mi][nf][j] + bias[o + j];
            }
        }
    }
}

// ---------------------------------------------------------------------------
// Flash attention v3b: 32x32x16 MFMA, swapped QK^T (S^T: q lane-local),
// no-max softmax (k pre-scaled by SCALE*log2e -> exp2), deferred l-sum,
// in-register P->PV via cvt-pack + shfl_xor(32) half-exchange (verified in
// round 4; permlane32_swap direction was the round-5 bug suspect).
// 32 q/wave, 4 waves (128 q/block), 1024 blocks -> 4 waves/SIMD.
// No K/V staging (L2-resident), no barriers in main loop.
// ---------------------------------------------------------------------------
__global__ __launch_bounds__(256, 4) void attn_kern(
    const short* __restrict__ qT, const short* __restrict__ kT,
    const short* __restrict__ vC, short* __restrict__ attT)
{
    __shared__ short Ol[4][32 * 64];
    const int wgid = blockIdx.x;
    const int nid = (wgid & 7) * 128 + (wgid >> 3);    // XCD-chunked swizzle (1024 = 8*128)
    const int qt = nid & 31, hh = (nid >> 5) & 7, b = nid >> 8;
    const int t = threadIdx.x, wave = t >> 6, lane = t & 63;
    const int h = lane >> 5, c = lane & 31;
    const int n0 = qt * 128 + wave * 32;

    const short* qp = qT + (size_t)b * NQ * CCH + hh * HDIM;
    const short* kp = kT + (size_t)b * NK * CCH + hh * HDIM;
    const short* vp = vC + (size_t)(b * NHD + hh) * 64 * NK;

    // Q B-frags (persist): B[k=d][n=q], lane holds q=c, d = dc*16 + h*8 + e
    b16x8 qf[3];
    #pragma unroll
    for (int dc = 0; dc < 3; dc++)
        qf[dc] = *(const b16x8*)(qp + (size_t)(n0 + c) * CCH + dc * 16 + h * 8);

    f32x16 O[2] = {};          // [dblock]
    float l_part = 0.f;

    for (int m0 = 0; m0 < NK; m0 += 64) {
        #pragma unroll
        for (int kb = 0; kb < 2; kb++) {
            const int mb = m0 + kb * 32;
            // K A-frags: A[m=key][k=d], lane: key = mb+c, d = dc*16 + h*8 + e
            b16x8 kf[3];
            #pragma unroll
            for (int dc = 0; dc < 3; dc++)
                kf[dc] = *(const b16x8*)(kp + (size_t)(mb + c) * CCH + dc * 16 + h * 8);
            f32x16 s = {};
            #pragma unroll
            for (int dc = 0; dc < 3; dc++)
                s = __builtin_amdgcn_mfma_f32_32x32x16_bf16(kf[dc], qf[dc], s, 0, 0, 0);
            // s[r] = S^T[key = mb + (r&3)+8*(r>>2)+4h][q = n0+c] * log2e
            float p[16]; float ls = 0.f;
            #pragma unroll
            for (int r = 0; r < 16; r++) { p[r] = exp2f(s[r]); ls += p[r]; }
            l_part += ls;
            // pack to PV A-frag: lane needs P[q=c][k = kk*16 + h*8 + e]
            b16x8 pfrag[2];
            #pragma unroll
            for (int kk = 0; kk < 2; kk++) {
                unsigned cw0 = pk2(p[kk * 8 + 0], p[kk * 8 + 1]);
                unsigned cw1 = pk2(p[kk * 8 + 2], p[kk * 8 + 3]);
                unsigned cw2 = pk2(p[kk * 8 + 4], p[kk * 8 + 5]);
                unsigned cw3 = pk2(p[kk * 8 + 6], p[kk * 8 + 7]);
                unsigned x0 = (unsigned)__shfl_xor((int)cw0, 32);
                unsigned x1 = (unsigned)__shfl_xor((int)cw1, 32);
                unsigned x2 = (unsigned)__shfl_xor((int)cw2, 32);
                unsigned x3 = (unsigned)__shfl_xor((int)cw3, 32);
                union { unsigned u[4]; b16x8 v; } w;
                w.u[0] = h ? x2 : cw0;
                w.u[1] = h ? x3 : cw1;
                w.u[2] = h ? cw2 : x0;
                w.u[3] = h ? cw3 : x1;
                pfrag[kk] = w.v;
            }
            // PV: O[q][d] += P[q][k] * V[k][d];  V B-frag: lane d = db*32+c
            #pragma unroll
            for (int kk = 0; kk < 2; kk++)
                #pragma unroll
                for (int db = 0; db < 2; db++) {
                    b16x8 vf = *(const b16x8*)(vp + (size_t)(db * 32 + c) * NK + mb + kk * 16 + h * 8);
                    O[db] = __builtin_amdgcn_mfma_f32_32x32x16_bf16(pfrag[kk], vf, O[db], 0, 0, 0);
                }
        }
    }

    // finish l (lane^32 holds the other half of the key range per r-slot)
    float lt = l_part + __shfl_xor(l_part, 32);
    float inv = 1.0f / lt;

    // normalize + bounce through LDS (swizzled) for coalesced b16x8 stores
    short* Olw = Ol[wave];
    #pragma unroll
    for (int r = 0; r < 16; r++) {
        int qrow = (r & 3) + 8 * (r >> 2) + 4 * h;
        float iq = __shfl(inv, qrow);
        #pragma unroll
        for (int db = 0; db < 2; db++) {
            int d = db * 32 + c;
            if (d < 48)
                Olw[qrow * 64 + (((d >> 3) ^ (qrow & 7)) * 8) + (d & 7)] =
                    (short)f2bf(O[db][r] * iq);
        }
    }
    __syncthreads();
    #pragma unroll
    for (int it = 0; it < 4; it++) {
        int idx = it * 64 + lane;
        int row = idx >> 3, c8 = idx & 7;
        if (c8 < 6) {
            b16x8 val = *(const b16x8*)(Olw + row * 64 + ((c8 ^ (row & 7)) * 8));
            *(b16x8*)(attT + ((size_t)b * NQ + n0 + row) * CCH + hh * HDIM + c8 * 8) = val;
        }
    }
}

// ---------------------------------------------------------------------------
extern "C" void kernel_launch(void* const* d_in, const int* in_sizes, int n_in,
                              void* d_out, int out_size, void* d_ws, size_t ws_size,
                              hipStream_t stream) {
    const float* x    = (const float*)d_in[0];
    const float* Wq   = (const float*)d_in[1];
    const float* Wk   = (const float*)d_in[2];
    const float* Wv   = (const float*)d_in[3];
    const float* Wsr  = (const float*)d_in[4];
    const float* bsr  = (const float*)d_in[5];
    const float* Wp   = (const float*)d_in[6];
    const float* bp   = (const float*)d_in[7];
    const float* relh = (const float*)d_in[8];
    const float* relw = (const float*)d_in[9];
    float* out = (float*)d_out;

    short* ws = (short*)d_ws;
    size_t off = 0;
    auto alloc = [&](size_t n) { short* p = ws + off; off += n; return p; };
    short* WqB  = alloc(147456);
    short* WkvB = alloc(294912);
    short* WsrB = alloc(589824);
    short* WpB  = alloc(147456);
    short* xT   = alloc((size_t)BATCH * NQ * CCH);
    short* xsrT = alloc((size_t)BATCH * NK * CCH);
    short* qTb  = alloc((size_t)BATCH * NQ * CCH);
    short* kTb  = alloc((size_t)BATCH * NK * CCH);
    short* vCb  = alloc((size_t)BATCH * NHD * 64 * NK);   // padded: 64 rows/head
    short* attT = alloc((size_t)BATCH * NQ * CCH);

    cvt_all<<<dim3(576, 5), 256, 0, stream>>>(Wq, Wk, Wv, Wsr, Wp, WqB, WkvB, WsrB, WpB);
    t1_kern<<<dim3(64, 6, BATCH), 256, 0, stream>>>(x, xT);
    // zero V pad rows (d=48..63 of each head)
    hipMemsetAsync(vCb, 0, (size_t)BATCH * NHD * 64 * NK * sizeof(short), stream);
    // SR conv as GEMM (+bsr), im2col gathered from xT, output xsrT[ssr][c]
    mfma_gemm<1, true><<<dim3(8, 3, BATCH), 256, 0, stream>>>(
        WsrB, xT, xsrT, nullptr, nullptr, bsr, nullptr, nullptr, 1536, NK);
    // Q projection -> qT[n][c]
    mfma_gemm<0, false><<<dim3(32, 3, BATCH), 256, 0, stream>>>(
        WqB, xT, qTb, nullptr, nullptr, nullptr, nullptr, nullptr, 384, NQ);
    // fused K (+pos, *SCALE*log2e) -> kT[m][c]  and  V -> vC[head*64+d][m]
    mfma_gemm<2, false><<<dim3(8, 6, BATCH), 256, 0, stream>>>(
        WkvB, xsrT, kTb, vCb, nullptr, nullptr, relh, relw, 384, NK);
    // attention (1024 blocks, XCD-swizzled)
    attn_kern<<<dim3(1024), 256, 0, stream>>>(qTb, kTb, vCb, attT);
    // output projection (+bp), f32 natural layout
    mfma_gemm<3, false><<<dim3(32, 3, BATCH), 256, 0, stream>>>(
        WpB, attT, nullptr, nullptr, out, bp, nullptr, nullptr, 384, NQ);
}

// Round 7
// 143.548 us; speedup vs baseline: 1.3398x; 1.3398x over previous
//
#include <hip/hip_runtime.h>
#include <hip/hip_bf16.h>
#include <math.h>

typedef __attribute__((ext_vector_type(8))) short b16x8;
typedef __attribute__((ext_vector_type(4))) short b16x4;
typedef __attribute__((ext_vector_type(4))) float floatx4;
typedef __attribute__((ext_vector_type(16))) float f32x16;

constexpr int BATCH = 4, CCH = 384, NQ = 4096, NHD = 8, HDIM = 48, NK = 1024;
constexpr float SCALE = 0.14433756729740643f;            // 48^-0.5
constexpr float SCALE_L2E = 0.14433756729740643f * 1.4426950408889634f; // *log2(e)

__device__ inline unsigned short f2bf(float f) {
    unsigned u = __builtin_bit_cast(unsigned, f);
    u += 0x7fffu + ((u >> 16) & 1u);
    return (unsigned short)(u >> 16);
}

__device__ inline unsigned pk2(float lo, float hi) {
    unsigned short a = __builtin_bit_cast(unsigned short, __float2bfloat16(lo));
    unsigned short b = __builtin_bit_cast(unsigned short, __float2bfloat16(hi));
    return ((unsigned)b << 16) | (unsigned)a;
}

__device__ __forceinline__ void g2lds16(const void* g, void* l) {
    __builtin_amdgcn_global_load_lds(
        (const __attribute__((address_space(1))) unsigned int*)g,
        (__attribute__((address_space(3))) unsigned int*)l, 16, 0, 0);
}

// ---------------------------------------------------------------------------
// Weight conversion fp32 -> bf16.  Wk,Wv stacked into WkvB[768][384].
// Wsr reordered to [o][pos*384+c]  (pos = i*2+j) so the conv-GEMM B operand
// becomes 4 contiguous xT row segments per 64-wide k chunk.
// ---------------------------------------------------------------------------
__global__ void cvt_all(const float* __restrict__ Wq, const float* __restrict__ Wk,
                        const float* __restrict__ Wv, const float* __restrict__ Wsr,
                        const float* __restrict__ Wp,
                        short* __restrict__ WqB, short* __restrict__ WkvB,
                        short* __restrict__ WsrB, short* __restrict__ WpB) {
    int job = blockIdx.y;
    if (job == 3) {
        for (int i = blockIdx.x * 256 + threadIdx.x; i < 589824; i += gridDim.x * 256) {
            int o = i / 1536, r = i - o * 1536;
            WsrB[o * 1536 + (r & 3) * 384 + (r >> 2)] = (short)f2bf(Wsr[i]);
        }
        return;
    }
    const float* src; short* dst;
    if (job == 0)      { src = Wq;  dst = WqB; }
    else if (job == 1) { src = Wk;  dst = WkvB; }
    else if (job == 2) { src = Wv;  dst = WkvB + 147456; }
    else               { src = Wp;  dst = WpB; }
    for (int i = blockIdx.x * 256 + threadIdx.x; i < 147456; i += gridDim.x * 256)
        dst[i] = (short)f2bf(src[i]);
}

// ---------------------------------------------------------------------------
// x [B][384][4096] f32  ->  xT [B][4096][384] bf16 (token-major)
// ---------------------------------------------------------------------------
__global__ void t1_kern(const float* __restrict__ x, short* __restrict__ xT) {
    int b = blockIdx.z, s = blockIdx.x * 64 + (threadIdx.x & 63);
    for (int c8 = blockIdx.y * 8 + (threadIdx.x >> 6); c8 < blockIdx.y * 8 + 8; c8 += 4) {
        b16x8 pk;
        #pragma unroll
        for (int e = 0; e < 8; e++)
            pk[e] = (short)f2bf(x[((size_t)b * CCH + c8 * 8 + e) * NQ + s]);
        *(b16x8*)(xT + ((size_t)b * NQ + s) * CCH + c8 * 8) = pk;
    }
}

// ---------------------------------------------------------------------------
// MFMA GEMM: Y[o][s] = sum_k A[o][k] * B[b][s][k];  128x128 tile, BK=64,
// 4 waves each 64x64 (4x4 frags of 16x16x32).  LDS XOR-swizzled.
// CONV: B operand gathered from xT (im2col on the fly, Wsr pos-major layout).
// EPI: 0 = bf16 transposed out Yt[s][o];  1 = +bias;  2 = fused KV (o<384: k
// with pos+scale*log2e -> Yt; o>=384: v -> Y2 channel-major);  3 = f32+bias.
// ---------------------------------------------------------------------------
template<int EPI, bool CONV>
__global__ __launch_bounds__(256, 2) void mfma_gemm(
    const short* __restrict__ A, const short* __restrict__ Bm,
    short* __restrict__ Yt, short* __restrict__ Y2, float* __restrict__ Yf,
    const float* __restrict__ bias, const float* __restrict__ relh,
    const float* __restrict__ relw, int Ksz, int S)
{
    __shared__ short At[128 * 64];
    __shared__ short Bt[128 * 64];
    const int b = blockIdx.z, o0 = blockIdx.y * 128, s0 = blockIdx.x * 128;
    const int t = threadIdx.x, wave = t >> 6, lane = t & 63, g = lane >> 4, li = lane & 15;
    const int wr = wave >> 1, wc = wave & 1;
    floatx4 acc[4][4] = {};
    const int row0 = t >> 3, ch = t & 7;
    const int wch = (ch ^ (row0 & 7)) * 8;  // (row0+32it)&7 == row0&7
    const short* Arow = A + (size_t)(o0 + row0) * Ksz + ch * 8;
    const short* Bbase = Bm + (size_t)b * S * Ksz;   // for CONV: == xT b-slab
    const short* Brow = Bbase + (size_t)(s0 + row0) * Ksz + ch * 8;

    for (int k0 = 0; k0 < Ksz; k0 += 64) {
        __syncthreads();
        #pragma unroll
        for (int it = 0; it < 4; it++) {
            int row = row0 + it * 32;
            *(b16x8*)(At + row * 64 + wch) = *(const b16x8*)(Arow + (size_t)it * 32 * Ksz + k0);
            if constexpr (CONV) {
                int ssr = s0 + row;
                int hs = ssr >> 5, wsv = ssr & 31;
                int k = k0 + ch * 8;
                int p = k / 384, coff = k - p * 384;
                const short* src = Bbase
                    + (size_t)((2 * hs + (p >> 1)) * 64 + 2 * wsv + (p & 1)) * 384 + coff;
                *(b16x8*)(Bt + row * 64 + wch) = *(const b16x8*)src;
            } else {
                *(b16x8*)(Bt + row * 64 + wch) = *(const b16x8*)(Brow + (size_t)it * 32 * Ksz + k0);
            }
        }
        __syncthreads();
        #pragma unroll
        for (int kk = 0; kk < 2; kk++) {
            b16x8 af[4], bf[4];
            #pragma unroll
            for (int mi = 0; mi < 4; mi++) {
                int r = wr * 64 + mi * 16 + li;
                af[mi] = *(const b16x8*)(At + r * 64 + (((kk * 4 + g) ^ (r & 7)) * 8));
            }
            #pragma unroll
            for (int nf = 0; nf < 4; nf++) {
                int r = wc * 64 + nf * 16 + li;
                bf[nf] = *(const b16x8*)(Bt + r * 64 + (((kk * 4 + g) ^ (r & 7)) * 8));
            }
            #pragma unroll
            for (int mi = 0; mi < 4; mi++)
                #pragma unroll
                for (int nf = 0; nf < 4; nf++)
                    acc[mi][nf] = __builtin_amdgcn_mfma_f32_16x16x32_bf16(af[mi], bf[nf], acc[mi][nf], 0, 0, 0);
        }
    }

    #pragma unroll
    for (int mi = 0; mi < 4; mi++) {
        #pragma unroll
        for (int nf = 0; nf < 4; nf++) {
            int o = o0 + wr * 64 + mi * 16 + g * 4;
            int s = s0 + wc * 64 + nf * 16 + li;
            if constexpr (EPI == 0 || EPI == 1) {
                b16x4 pk;
                #pragma unroll
                for (int j = 0; j < 4; j++) {
                    float v = acc[mi][nf][j];
                    if constexpr (EPI == 1) v += bias[o + j];
                    pk[j] = (short)f2bf(v);
                }
                *(b16x4*)(Yt + ((size_t)b * S + s) * CCH + o) = pk;
            } else if constexpr (EPI == 2) {
                if (o0 < 384) {
                    // pos[m] = rel_h[o][m & 31] + rel_w[o][m >> 5]
                    int hs = s >> 5, wsv = s & 31;
                    b16x4 pk;
                    #pragma unroll
                    for (int j = 0; j < 4; j++)
                        pk[j] = (short)f2bf((acc[mi][nf][j] + relh[(o + j) * 32 + wsv]
                                             + relw[(o + j) * 32 + hs]) * SCALE_L2E);
                    *(b16x4*)(Yt + ((size_t)b * S + s) * CCH + o) = pk;
                } else {
                    #pragma unroll
                    for (int j = 0; j < 4; j++)
                        Y2[((size_t)b * CCH + (o - 384 + j)) * NK + s] = (short)f2bf(acc[mi][nf][j]);
                }
            } else {
                #pragma unroll
                for (int j = 0; j < 4; j++)
                    Yf[((size_t)b * CCH + o + j) * (size_t)S + s] = acc[mi][nf][j] + bias[o + j];
            }
        }
    }
}

// ---------------------------------------------------------------------------
// Flash attention v4: round-6 register structure + LDS-staged K/V tiles
// (shared by all 4 waves -> 4x less L2 traffic).  64-key tiles, double-
// buffered via global_load_lds (linear dest, inverse-swizzled source),
// XOR chunk swizzle on ds_read_b128.  V pad rows d=48..63 zeroed once.
// 32 q/wave, 128 q/block, 1024 blocks.
// ---------------------------------------------------------------------------
__global__ __launch_bounds__(256, 4) void attn_kern(
    const short* __restrict__ qT, const short* __restrict__ kT,
    const short* __restrict__ vC, short* __restrict__ attT)
{
    // [buf][0]=K tile (64 keys x 64d-pad), [buf][1]=V tile (64 d x 64 keys)
    __shared__ short lds[2][2][64 * 64];
    const int wgid = blockIdx.x;
    const int nid = (wgid & 7) * 128 + (wgid >> 3);    // XCD-chunked swizzle (1024 = 8*128)
    const int qt = nid & 31, hh = (nid >> 5) & 7, b = nid >> 8;
    const int t = threadIdx.x, wave = t >> 6, lane = t & 63;
    const int h = lane >> 5, c = lane & 31;
    const int n0 = qt * 128 + wave * 32;

    const short* qp = qT + (size_t)b * NQ * CCH + hh * HDIM;
    const short* kp = kT + (size_t)b * NK * CCH + hh * HDIM;
    const short* vp = vC + ((size_t)b * CCH + hh * HDIM) * NK;

    // zero V pad rows (d=48..63) of both buffers, once
    {
        int bufi = t >> 7, offs = 3072 + (t & 127) * 8;
        *(b16x8*)(&lds[bufi][1][offs]) = b16x8{};
    }

    // Q B-frags (persist): B[k=d][n=q], lane holds q=c, d = dc*16 + h*8 + e
    b16x8 qf[3];
    #pragma unroll
    for (int dc = 0; dc < 3; dc++)
        qf[dc] = *(const b16x8*)(qp + (size_t)(n0 + c) * CCH + dc * 16 + h * 8);

    // stage tile m0 into buffer bi:  LDS[row][chunk] holds content chunk^(row&7)
    auto stage = [&](int m0, int bi) {
        #pragma unroll
        for (int it = 0; it < 2; it++) {
            int task = it * 256 + wave * 64 + lane;
            int row = task >> 3, chunk = task & 7;
            int cont = chunk ^ (row & 7);
            if (cont < 6)   // K has 6 real 16B chunks (48 d)
                g2lds16(kp + (size_t)(m0 + row) * CCH + cont * 8, &lds[bi][0][task * 8]);
        }
        #pragma unroll
        for (int it = 0; it < 2; it++) {
            int task = it * 256 + wave * 64 + lane;
            int row = task >> 3, chunk = task & 7;
            if (row < 48)   // V real d rows; 48..63 stay zero
                g2lds16(vp + (size_t)row * NK + m0 + ((chunk ^ (row & 7)) * 8),
                        &lds[bi][1][task * 8]);
        }
    };

    f32x16 O[2] = {};          // [dblock]
    float l_part = 0.f;

    stage(0, 0);
    for (int tt = 0; tt < 16; ++tt) {
        __syncthreads();       // drains global_load_lds (vmcnt) + joins waves
        if (tt < 15) stage((tt + 1) * 64, (tt + 1) & 1);
        const short* Kb = lds[tt & 1][0];
        const short* Vb = lds[tt & 1][1];
        #pragma unroll
        for (int kb = 0; kb < 2; kb++) {
            // K A-frags from LDS: row = kb*32+c, content chunk dc*2+h
            b16x8 kf[3];
            #pragma unroll
            for (int dc = 0; dc < 3; dc++)
                kf[dc] = *(const b16x8*)(Kb + (kb * 32 + c) * 64 + (((dc * 2 + h) ^ (c & 7)) * 8));
            f32x16 s = {};
            #pragma unroll
            for (int dc = 0; dc < 3; dc++)
                s = __builtin_amdgcn_mfma_f32_32x32x16_bf16(kf[dc], qf[dc], s, 0, 0, 0);
            // s[r] = S^T[key = kb*32 + (r&3)+8*(r>>2)+4h][q = n0+c] * log2e
            float p[16]; float ls = 0.f;
            #pragma unroll
            for (int r = 0; r < 16; r++) { p[r] = exp2f(s[r]); ls += p[r]; }
            l_part += ls;
            // pack to PV A-frag: lane needs P[q=c][k = kk*16 + h*8 + e]
            b16x8 pfrag[2];
            #pragma unroll
            for (int kk = 0; kk < 2; kk++) {
                unsigned cw0 = pk2(p[kk * 8 + 0], p[kk * 8 + 1]);
                unsigned cw1 = pk2(p[kk * 8 + 2], p[kk * 8 + 3]);
                unsigned cw2 = pk2(p[kk * 8 + 4], p[kk * 8 + 5]);
                unsigned cw3 = pk2(p[kk * 8 + 6], p[kk * 8 + 7]);
                unsigned x0 = (unsigned)__shfl_xor((int)cw0, 32);
                unsigned x1 = (unsigned)__shfl_xor((int)cw1, 32);
                unsigned x2 = (unsigned)__shfl_xor((int)cw2, 32);
                unsigned x3 = (unsigned)__shfl_xor((int)cw3, 32);
                union { unsigned u[4]; b16x8 v; } w;
                w.u[0] = h ? x2 : cw0;
                w.u[1] = h ? x3 : cw1;
                w.u[2] = h ? cw2 : x0;
                w.u[3] = h ? cw3 : x1;
                pfrag[kk] = w.v;
            }
            // PV: V B-frags from LDS: row(d) = db*32+c, key chunk kb*4+kk*2+h
            #pragma unroll
            for (int kk = 0; kk < 2; kk++)
                #pragma unroll
                for (int db = 0; db < 2; db++) {
                    b16x8 vf = *(const b16x8*)(Vb + (db * 32 + c) * 64
                                               + (((kb * 4 + kk * 2 + h) ^ (c & 7)) * 8));
                    O[db] = __builtin_amdgcn_mfma_f32_32x32x16_bf16(pfrag[kk], vf, O[db], 0, 0, 0);
                }
        }
    }

    // finish l (lane^32 holds the other half of the key range per r-slot)
    float lt = l_part + __shfl_xor(l_part, 32);
    float inv = 1.0f / lt;

    // normalize + bounce through LDS (reuse buf0 area; wave-private segment)
    short* Olw = ((short*)lds) + wave * 2048;
    #pragma unroll
    for (int r = 0; r < 16; r++) {
        int qrow = (r & 3) + 8 * (r >> 2) + 4 * h;
        float iq = __shfl(inv, qrow);
        #pragma unroll
        for (int db = 0; db < 2; db++) {
            int d = db * 32 + c;
            if (d < 48)
                Olw[qrow * 64 + (((d >> 3) ^ (qrow & 7)) * 8) + (d & 7)] =
                    (short)f2bf(O[db][r] * iq);
        }
    }
    __syncthreads();
    #pragma unroll
    for (int it = 0; it < 4; it++) {
        int idx = it * 64 + lane;
        int row = idx >> 3, c8 = idx & 7;
        if (c8 < 6) {
            b16x8 val = *(const b16x8*)(Olw + row * 64 + ((c8 ^ (row & 7)) * 8));
            *(b16x8*)(attT + ((size_t)b * NQ + n0 + row) * CCH + hh * HDIM + c8 * 8) = val;
        }
    }
}

// ---------------------------------------------------------------------------
extern "C" void kernel_launch(void* const* d_in, const int* in_sizes, int n_in,
                              void* d_out, int out_size, void* d_ws, size_t ws_size,
                              hipStream_t stream) {
    const float* x    = (const float*)d_in[0];
    const float* Wq   = (const float*)d_in[1];
    const float* Wk   = (const float*)d_in[2];
    const float* Wv   = (const float*)d_in[3];
    const float* Wsr  = (const float*)d_in[4];
    const float* bsr  = (const float*)d_in[5];
    const float* Wp   = (const float*)d_in[6];
    const float* bp   = (const float*)d_in[7];
    const float* relh = (const float*)d_in[8];
    const float* relw = (const float*)d_in[9];
    float* out = (float*)d_out;

    short* ws = (short*)d_ws;
    size_t off = 0;
    auto alloc = [&](size_t n) { short* p = ws + off; off += n; return p; };
    short* WqB  = alloc(147456);
    short* WkvB = alloc(294912);
    short* WsrB = alloc(589824);
    short* WpB  = alloc(147456);
    short* xT   = alloc((size_t)BATCH * NQ * CCH);
    short* xsrT = alloc((size_t)BATCH * NK * CCH);
    short* qTb  = alloc((size_t)BATCH * NQ * CCH);
    short* kTb  = alloc((size_t)BATCH * NK * CCH);
    short* vCb  = alloc((size_t)BATCH * CCH * NK);
    short* attT = alloc((size_t)BATCH * NQ * CCH);

    cvt_all<<<dim3(576, 5), 256, 0, stream>>>(Wq, Wk, Wv, Wsr, Wp, WqB, WkvB, WsrB, WpB);
    t1_kern<<<dim3(64, 6, BATCH), 256, 0, stream>>>(x, xT);
    // SR conv as GEMM (+bsr), im2col gathered from xT, output xsrT[ssr][c]
    mfma_gemm<1, true><<<dim3(8, 3, BATCH), 256, 0, stream>>>(
        WsrB, xT, xsrT, nullptr, nullptr, bsr, nullptr, nullptr, 1536, NK);
    // Q projection -> qT[n][c]
    mfma_gemm<0, false><<<dim3(32, 3, BATCH), 256, 0, stream>>>(
        WqB, xT, qTb, nullptr, nullptr, nullptr, nullptr, nullptr, 384, NQ);
    // fused K (+pos, *SCALE*log2e) -> kT[m][c]  and  V -> vC[c][m]
    mfma_gemm<2, false><<<dim3(8, 6, BATCH), 256, 0, stream>>>(
        WkvB, xsrT, kTb, vCb, nullptr, nullptr, relh, relw, 384, NK);
    // attention (1024 blocks, XCD-swizzled, LDS-staged K/V)
    attn_kern<<<dim3(1024), 256, 0, stream>>>(qTb, kTb, vCb, attT);
    // output projection (+bp), f32 natural layout
    mfma_gemm<3, false><<<dim3(32, 3, BATCH), 256, 0, stream>>>(
        WpB, attT, nullptr, nullptr, out, bp, nullptr, nullptr, 384, NQ);
}

// Round 8
// 140.111 us; speedup vs baseline: 1.3727x; 1.0245x over previous
//
#include <hip/hip_runtime.h>
#include <hip/hip_bf16.h>
#include <math.h>

typedef __attribute__((ext_vector_type(8))) short b16x8;
typedef __attribute__((ext_vector_type(4))) short b16x4;
typedef __attribute__((ext_vector_type(4))) float floatx4;
typedef __attribute__((ext_vector_type(16))) float f32x16;

constexpr int BATCH = 4, CCH = 384, NQ = 4096, NHD = 8, HDIM = 48, NK = 1024;
constexpr float SCALE = 0.14433756729740643f;            // 48^-0.5
constexpr float SCALE_L2E = 0.14433756729740643f * 1.4426950408889634f; // *log2(e)

__device__ inline unsigned short f2bf(float f) {
    unsigned u = __builtin_bit_cast(unsigned, f);
    u += 0x7fffu + ((u >> 16) & 1u);
    return (unsigned short)(u >> 16);
}

__device__ inline unsigned pk2(float lo, float hi) {
    unsigned short a = __builtin_bit_cast(unsigned short, __float2bfloat16(lo));
    unsigned short b = __builtin_bit_cast(unsigned short, __float2bfloat16(hi));
    return ((unsigned)b << 16) | (unsigned)a;
}

__device__ __forceinline__ void g2lds16(const void* g, void* l) {
    __builtin_amdgcn_global_load_lds(
        (const __attribute__((address_space(1))) unsigned int*)g,
        (__attribute__((address_space(3))) unsigned int*)l, 16, 0, 0);
}

// ---------------------------------------------------------------------------
// Weight conversion fp32 -> bf16.  Wk,Wv stacked into WkvB[768][384].
// Wsr reordered to [o][pos*384+c]  (pos = i*2+j) so the conv-GEMM B operand
// becomes 4 contiguous xT row segments per 64-wide k chunk.
// ---------------------------------------------------------------------------
__global__ void cvt_all(const float* __restrict__ Wq, const float* __restrict__ Wk,
                        const float* __restrict__ Wv, const float* __restrict__ Wsr,
                        const float* __restrict__ Wp,
                        short* __restrict__ WqB, short* __restrict__ WkvB,
                        short* __restrict__ WsrB, short* __restrict__ WpB) {
    int job = blockIdx.y;
    if (job == 3) {
        for (int i = blockIdx.x * 256 + threadIdx.x; i < 589824; i += gridDim.x * 256) {
            int o = i / 1536, r = i - o * 1536;
            WsrB[o * 1536 + (r & 3) * 384 + (r >> 2)] = (short)f2bf(Wsr[i]);
        }
        return;
    }
    const float* src; short* dst;
    if (job == 0)      { src = Wq;  dst = WqB; }
    else if (job == 1) { src = Wk;  dst = WkvB; }
    else if (job == 2) { src = Wv;  dst = WkvB + 147456; }
    else               { src = Wp;  dst = WpB; }
    for (int i = blockIdx.x * 256 + threadIdx.x; i < 147456; i += gridDim.x * 256)
        dst[i] = (short)f2bf(src[i]);
}

// ---------------------------------------------------------------------------
// x [B][384][4096] f32  ->  xT [B][4096][384] bf16 (token-major)
// ---------------------------------------------------------------------------
__global__ void t1_kern(const float* __restrict__ x, short* __restrict__ xT) {
    int b = blockIdx.z, s = blockIdx.x * 64 + (threadIdx.x & 63);
    for (int c8 = blockIdx.y * 8 + (threadIdx.x >> 6); c8 < blockIdx.y * 8 + 8; c8 += 4) {
        b16x8 pk;
        #pragma unroll
        for (int e = 0; e < 8; e++)
            pk[e] = (short)f2bf(x[((size_t)b * CCH + c8 * 8 + e) * NQ + s]);
        *(b16x8*)(xT + ((size_t)b * NQ + s) * CCH + c8 * 8) = pk;
    }
}

// ---------------------------------------------------------------------------
// MFMA GEMM: Y[o][s] = sum_k A[o][k] * B[b][s][k];  128x128 tile, BK=64,
// 4 waves each 64x64 (4x4 frags of 16x16x32).  LDS XOR-swizzled.
// CONV: B operand gathered from xT (im2col on the fly, Wsr pos-major layout).
// EPI: 0 = bf16 transposed out Yt[s][o];  1 = +bias;  2 = fused KV (o<384: k
// with pos+scale*log2e -> Yt; o>=384: v -> Y2 channel-major);  3 = f32+bias.
// ---------------------------------------------------------------------------
template<int EPI, bool CONV>
__global__ __launch_bounds__(256, 2) void mfma_gemm(
    const short* __restrict__ A, const short* __restrict__ Bm,
    short* __restrict__ Yt, short* __restrict__ Y2, float* __restrict__ Yf,
    const float* __restrict__ bias, const float* __restrict__ relh,
    const float* __restrict__ relw, int Ksz, int S)
{
    __shared__ short At[128 * 64];
    __shared__ short Bt[128 * 64];
    const int b = blockIdx.z, o0 = blockIdx.y * 128, s0 = blockIdx.x * 128;
    const int t = threadIdx.x, wave = t >> 6, lane = t & 63, g = lane >> 4, li = lane & 15;
    const int wr = wave >> 1, wc = wave & 1;
    floatx4 acc[4][4] = {};
    const int row0 = t >> 3, ch = t & 7;
    const int wch = (ch ^ (row0 & 7)) * 8;  // (row0+32it)&7 == row0&7
    const short* Arow = A + (size_t)(o0 + row0) * Ksz + ch * 8;
    const short* Bbase = Bm + (size_t)b * S * Ksz;   // for CONV: == xT b-slab
    const short* Brow = Bbase + (size_t)(s0 + row0) * Ksz + ch * 8;

    for (int k0 = 0; k0 < Ksz; k0 += 64) {
        __syncthreads();
        #pragma unroll
        for (int it = 0; it < 4; it++) {
            int row = row0 + it * 32;
            *(b16x8*)(At + row * 64 + wch) = *(const b16x8*)(Arow + (size_t)it * 32 * Ksz + k0);
            if constexpr (CONV) {
                int ssr = s0 + row;
                int hs = ssr >> 5, wsv = ssr & 31;
                int k = k0 + ch * 8;
                int p = k / 384, coff = k - p * 384;
                const short* src = Bbase
                    + (size_t)((2 * hs + (p >> 1)) * 64 + 2 * wsv + (p & 1)) * 384 + coff;
                *(b16x8*)(Bt + row * 64 + wch) = *(const b16x8*)src;
            } else {
                *(b16x8*)(Bt + row * 64 + wch) = *(const b16x8*)(Brow + (size_t)it * 32 * Ksz + k0);
            }
        }
        __syncthreads();
        #pragma unroll
        for (int kk = 0; kk < 2; kk++) {
            b16x8 af[4], bf[4];
            #pragma unroll
            for (int mi = 0; mi < 4; mi++) {
                int r = wr * 64 + mi * 16 + li;
                af[mi] = *(const b16x8*)(At + r * 64 + (((kk * 4 + g) ^ (r & 7)) * 8));
            }
            #pragma unroll
            for (int nf = 0; nf < 4; nf++) {
                int r = wc * 64 + nf * 16 + li;
                bf[nf] = *(const b16x8*)(Bt + r * 64 + (((kk * 4 + g) ^ (r & 7)) * 8));
            }
            #pragma unroll
            for (int mi = 0; mi < 4; mi++)
                #pragma unroll
                for (int nf = 0; nf < 4; nf++)
                    acc[mi][nf] = __builtin_amdgcn_mfma_f32_16x16x32_bf16(af[mi], bf[nf], acc[mi][nf], 0, 0, 0);
        }
    }

    #pragma unroll
    for (int mi = 0; mi < 4; mi++) {
        #pragma unroll
        for (int nf = 0; nf < 4; nf++) {
            int o = o0 + wr * 64 + mi * 16 + g * 4;
            int s = s0 + wc * 64 + nf * 16 + li;
            if constexpr (EPI == 0 || EPI == 1) {
                b16x4 pk;
                #pragma unroll
                for (int j = 0; j < 4; j++) {
                    float v = acc[mi][nf][j];
                    if constexpr (EPI == 1) v += bias[o + j];
                    pk[j] = (short)f2bf(v);
                }
                *(b16x4*)(Yt + ((size_t)b * S + s) * CCH + o) = pk;
            } else if constexpr (EPI == 2) {
                if (o0 < 384) {
                    // pos[m] = rel_h[o][m & 31] + rel_w[o][m >> 5]
                    int hs = s >> 5, wsv = s & 31;
                    b16x4 pk;
                    #pragma unroll
                    for (int j = 0; j < 4; j++)
                        pk[j] = (short)f2bf((acc[mi][nf][j] + relh[(o + j) * 32 + wsv]
                                             + relw[(o + j) * 32 + hs]) * SCALE_L2E);
                    *(b16x4*)(Yt + ((size_t)b * S + s) * CCH + o) = pk;
                } else {
                    #pragma unroll
                    for (int j = 0; j < 4; j++)
                        Y2[((size_t)b * CCH + (o - 384 + j)) * NK + s] = (short)f2bf(acc[mi][nf][j]);
                }
            } else {
                #pragma unroll
                for (int j = 0; j < 4; j++)
                    Yf[((size_t)b * CCH + o + j) * (size_t)S + s] = acc[mi][nf][j] + bias[o + j];
            }
        }
    }
}

// ---------------------------------------------------------------------------
// Flash attention v5: LDS-staged K/V (chunk-major, conflict-free ds_read),
// K rows permuted at stage time (swap bits 2,3) so S^T slots align directly
// with the PV A-fragment -> ZERO cross-lane exchange.  l computed by the PV
// MFMA itself via a ones-row at V d=48.  32 q/wave, 128 q/block, 1024 blocks.
// ---------------------------------------------------------------------------
__global__ __launch_bounds__(256, 4) void attn_kern(
    const short* __restrict__ qT, const short* __restrict__ kT,
    const short* __restrict__ vC, short* __restrict__ attT)
{
    __shared__ short Kl[2][6 * 64 * 8];   // [buf][d-chunk 0..5][row][8]
    __shared__ short Vl[2][8 * 64 * 8];   // [buf][key-chunk 0..7][d-row][8]
    const int wgid = blockIdx.x;
    const int nid = (wgid & 7) * 128 + (wgid >> 3);    // XCD-chunked swizzle
    const int qt = nid & 31, hh = (nid >> 5) & 7, b = nid >> 8;
    const int t = threadIdx.x, wave = t >> 6, lane = t & 63;
    const int h = lane >> 5, c = lane & 31;
    const int n0 = qt * 128 + wave * 32;

    const short* qp = qT + (size_t)b * NQ * CCH + hh * HDIM;
    const short* kp = kT + (size_t)b * NK * CCH + hh * HDIM;
    const short* vp = vC + ((size_t)b * CCH + hh * HDIM) * NK;

    // init V pad rows 48..63 of every key-chunk: row 48 = 1.0 (l-column), rest 0
    {
        int bufi = t >> 7, rem = t & 127;          // 128 slots = 8 chunks x 16 rows
        int ch = rem >> 4, row = 48 + (rem & 15);
        b16x8 val = {};
        if (row == 48)
            #pragma unroll
            for (int e = 0; e < 8; e++) val[e] = (short)0x3F80;
        *(b16x8*)(&Vl[bufi][(ch * 64 + row) * 8]) = val;
    }

    // Q B-frags (persist): B[k=d][n=q], lane holds q=c, d = dc*16 + h*8 + e
    b16x8 qf[3];
    #pragma unroll
    for (int dc = 0; dc < 3; dc++)
        qf[dc] = *(const b16x8*)(qp + (size_t)(n0 + c) * CCH + dc * 16 + h * 8);

    // stage tile m0 -> buffer bi.  K: LDS row holds global key with bits 2,3
    // swapped (pre-permuted SOURCE, linear dest).  V: natural key columns.
    auto stage = [&](int m0, int bi) {
        #pragma unroll
        for (int it = 0; it < 2; it++) {
            int task = it * 256 + wave * 64 + lane;
            int ch = task >> 6, row = task & 63;
            if (ch < 6) {
                int key = (row & 51) | ((row & 4) << 1) | ((row & 8) >> 1);
                g2lds16(kp + (size_t)(m0 + key) * CCH + ch * 8, &Kl[bi][task * 8]);
            }
        }
        #pragma unroll
        for (int it = 0; it < 2; it++) {
            int task = it * 256 + wave * 64 + lane;
            int ch = task >> 6, row = task & 63;
            if (row < 48)
                g2lds16(vp + (size_t)row * NK + m0 + ch * 8, &Vl[bi][task * 8]);
        }
    };

    f32x16 O[2] = {};          // [dblock];  O[1] col c=16 accumulates l

    stage(0, 0);
    for (int tt = 0; tt < 16; ++tt) {
        __syncthreads();       // drains global_load_lds + joins waves
        if (tt < 15) stage((tt + 1) * 64, (tt + 1) & 1);
        const short* Kb = Kl[tt & 1];
        const short* Vb = Vl[tt & 1];
        #pragma unroll
        for (int kb = 0; kb < 2; kb++) {
            // K A-frags: chunk dc*2+h, row kb*32+c  (contiguous per half -> no conflicts)
            b16x8 kf[3];
            #pragma unroll
            for (int dc = 0; dc < 3; dc++)
                kf[dc] = *(const b16x8*)(Kb + (((dc * 2 + h) * 64) + kb * 32 + c) * 8);
            f32x16 s = {};
            #pragma unroll
            for (int dc = 0; dc < 3; dc++)
                s = __builtin_amdgcn_mfma_f32_32x32x16_bf16(kf[dc], qf[dc], s, 0, 0, 0);
            // slot r holds P[permuted key][q=c]; permutation aligns r=kk*8+e
            // with PV A-position (kk, h, e) -> pack pairs directly, no exchange
            float p[16];
            #pragma unroll
            for (int r = 0; r < 16; r++) p[r] = exp2f(s[r]);
            b16x8 pfrag[2];
            #pragma unroll
            for (int kk = 0; kk < 2; kk++) {
                union { unsigned u[4]; b16x8 v; } w;
                #pragma unroll
                for (int wd = 0; wd < 4; wd++)
                    w.u[wd] = pk2(p[kk * 8 + wd * 2], p[kk * 8 + wd * 2 + 1]);
                pfrag[kk] = w.v;
            }
            // PV: V B-frags: chunk kb*4+kk*2+h, row db*32+c (conflict-free)
            #pragma unroll
            for (int kk = 0; kk < 2; kk++)
                #pragma unroll
                for (int db = 0; db < 2; db++) {
                    b16x8 vf = *(const b16x8*)(Vb + (((kb * 4 + kk * 2 + h) * 64) + db * 32 + c) * 8);
                    O[db] = __builtin_amdgcn_mfma_f32_32x32x16_bf16(pfrag[kk], vf, O[db], 0, 0, 0);
                }
        }
    }

    __syncthreads();   // all waves done reading V before Olw overlays it
    // l[q-slot r] lives in lane (h, c=16) at O[1][r]; broadcast + normalize
    short* Olw = ((short*)Vl) + wave * 2048;
    #pragma unroll
    for (int r = 0; r < 16; r++) {
        int qrow = (r & 3) + 8 * (r >> 2) + 4 * h;
        float lr = __shfl(O[1][r], (lane & 32) | 16);
        float iq = 1.0f / lr;
        #pragma unroll
        for (int db = 0; db < 2; db++) {
            int d = db * 32 + c;
            if (d < 48)
                Olw[qrow * 64 + (((d >> 3) ^ (qrow & 7)) * 8) + (d & 7)] =
                    (short)f2bf(O[db][r] * iq);
        }
    }
    __syncthreads();
    #pragma unroll
    for (int it = 0; it < 4; it++) {
        int idx = it * 64 + lane;
        int row = idx >> 3, c8 = idx & 7;
        if (c8 < 6) {
            b16x8 val = *(const b16x8*)(Olw + row * 64 + ((c8 ^ (row & 7)) * 8));
            *(b16x8*)(attT + ((size_t)b * NQ + n0 + row) * CCH + hh * HDIM + c8 * 8) = val;
        }
    }
}

// ---------------------------------------------------------------------------
extern "C" void kernel_launch(void* const* d_in, const int* in_sizes, int n_in,
                              void* d_out, int out_size, void* d_ws, size_t ws_size,
                              hipStream_t stream) {
    const float* x    = (const float*)d_in[0];
    const float* Wq   = (const float*)d_in[1];
    const float* Wk   = (const float*)d_in[2];
    const float* Wv   = (const float*)d_in[3];
    const float* Wsr  = (const float*)d_in[4];
    const float* bsr  = (const float*)d_in[5];
    const float* Wp   = (const float*)d_in[6];
    const float* bp   = (const float*)d_in[7];
    const float* relh = (const float*)d_in[8];
    const float* relw = (const float*)d_in[9];
    float* out = (float*)d_out;

    short* ws = (short*)d_ws;
    size_t off = 0;
    auto alloc = [&](size_t n) { short* p = ws + off; off += n; return p; };
    short* WqB  = alloc(147456);
    short* WkvB = alloc(294912);
    short* WsrB = alloc(589824);
    short* WpB  = alloc(147456);
    short* xT   = alloc((size_t)BATCH * NQ * CCH);
    short* xsrT = alloc((size_t)BATCH * NK * CCH);
    short* qTb  = alloc((size_t)BATCH * NQ * CCH);
    short* kTb  = alloc((size_t)BATCH * NK * CCH);
    short* vCb  = alloc((size_t)BATCH * CCH * NK);
    short* attT = alloc((size_t)BATCH * NQ * CCH);

    cvt_all<<<dim3(576, 5), 256, 0, stream>>>(Wq, Wk, Wv, Wsr, Wp, WqB, WkvB, WsrB, WpB);
    t1_kern<<<dim3(64, 6, BATCH), 256, 0, stream>>>(x, xT);
    // SR conv as GEMM (+bsr), im2col gathered from xT, output xsrT[ssr][c]
    mfma_gemm<1, true><<<dim3(8, 3, BATCH), 256, 0, stream>>>(
        WsrB, xT, xsrT, nullptr, nullptr, bsr, nullptr, nullptr, 1536, NK);
    // Q projection -> qT[n][c]
    mfma_gemm<0, false><<<dim3(32, 3, BATCH), 256, 0, stream>>>(
        WqB, xT, qTb, nullptr, nullptr, nullptr, nullptr, nullptr, 384, NQ);
    // fused K (+pos, *SCALE*log2e) -> kT[m][c]  and  V -> vC[c][m]
    mfma_gemm<2, false><<<dim3(8, 6, BATCH), 256, 0, stream>>>(
        WkvB, xsrT, kTb, vCb, nullptr, nullptr, relh, relw, 384, NK);
    // attention (1024 blocks, XCD-swizzled, LDS-staged K/V)
    attn_kern<<<dim3(1024), 256, 0, stream>>>(qTb, kTb, vCb, attT);
    // output projection (+bp), f32 natural layout
    mfma_gemm<3, false><<<dim3(32, 3, BATCH), 256, 0, stream>>>(
        WpB, attT, nullptr, nullptr, out, bp, nullptr, nullptr, 384, NQ);
}

// Round 9
// 138.565 us; speedup vs baseline: 1.3880x; 1.0112x over previous
//
#include <hip/hip_runtime.h>
#include <hip/hip_bf16.h>
#include <math.h>

typedef __attribute__((ext_vector_type(8))) short b16x8;
typedef __attribute__((ext_vector_type(4))) short b16x4;
typedef __attribute__((ext_vector_type(4))) float floatx4;
typedef __attribute__((ext_vector_type(16))) float f32x16;

constexpr int BATCH = 4, CCH = 384, NQ = 4096, NHD = 8, HDIM = 48, NK = 1024;
constexpr float SCALE = 0.14433756729740643f;            // 48^-0.5
constexpr float SCALE_L2E = 0.14433756729740643f * 1.4426950408889634f; // *log2(e)

__device__ inline unsigned short f2bf(float f) {
    unsigned u = __builtin_bit_cast(unsigned, f);
    u += 0x7fffu + ((u >> 16) & 1u);
    return (unsigned short)(u >> 16);
}

__device__ inline unsigned pk2(float lo, float hi) {
    unsigned short a = __builtin_bit_cast(unsigned short, __float2bfloat16(lo));
    unsigned short b = __builtin_bit_cast(unsigned short, __float2bfloat16(hi));
    return ((unsigned)b << 16) | (unsigned)a;
}

__device__ __forceinline__ void g2lds16(const void* g, void* l) {
    __builtin_amdgcn_global_load_lds(
        (const __attribute__((address_space(1))) unsigned int*)g,
        (__attribute__((address_space(3))) unsigned int*)l, 16, 0, 0);
}

// ---------------------------------------------------------------------------
// Weight conversion fp32 -> bf16.  Wk,Wv stacked into WkvB[768][384].
// Wsr reordered to [o][pos*384+c]  (pos = i*2+j) so the conv-GEMM B operand
// becomes 4 contiguous xT row segments per 64-wide k chunk.
// ---------------------------------------------------------------------------
__global__ void cvt_all(const float* __restrict__ Wq, const float* __restrict__ Wk,
                        const float* __restrict__ Wv, const float* __restrict__ Wsr,
                        const float* __restrict__ Wp,
                        short* __restrict__ WqB, short* __restrict__ WkvB,
                        short* __restrict__ WsrB, short* __restrict__ WpB) {
    int job = blockIdx.y;
    if (job == 3) {
        for (int i = blockIdx.x * 256 + threadIdx.x; i < 589824; i += gridDim.x * 256) {
            int o = i / 1536, r = i - o * 1536;
            WsrB[o * 1536 + (r & 3) * 384 + (r >> 2)] = (short)f2bf(Wsr[i]);
        }
        return;
    }
    const float* src; short* dst;
    if (job == 0)      { src = Wq;  dst = WqB; }
    else if (job == 1) { src = Wk;  dst = WkvB; }
    else if (job == 2) { src = Wv;  dst = WkvB + 147456; }
    else               { src = Wp;  dst = WpB; }
    for (int i = blockIdx.x * 256 + threadIdx.x; i < 147456; i += gridDim.x * 256)
        dst[i] = (short)f2bf(src[i]);
}

// ---------------------------------------------------------------------------
// x [B][384][4096] f32  ->  xT [B][4096][384] bf16 (token-major)
// ---------------------------------------------------------------------------
__global__ void t1_kern(const float* __restrict__ x, short* __restrict__ xT) {
    int b = blockIdx.z, s = blockIdx.x * 64 + (threadIdx.x & 63);
    for (int c8 = blockIdx.y * 8 + (threadIdx.x >> 6); c8 < blockIdx.y * 8 + 8; c8 += 4) {
        b16x8 pk;
        #pragma unroll
        for (int e = 0; e < 8; e++)
            pk[e] = (short)f2bf(x[((size_t)b * CCH + c8 * 8 + e) * NQ + s]);
        *(b16x8*)(xT + ((size_t)b * NQ + s) * CCH + c8 * 8) = pk;
    }
}

// ---------------------------------------------------------------------------
// MFMA GEMM: Y[o][s] = sum_k A[o][k] * B[b][s][k];  128x128 tile, BK=64,
// 4 waves each 64x64 (4x4 frags of 16x16x32).  Staging via global_load_lds
// (linear LDS dest, inverse-XOR-swizzled per-lane SOURCE; read side applies
// the same involution).  CONV: im2col gathered from xT on the fly.
// EPI: 0 = bf16 transposed out Yt[s][o];  1 = +bias;  2 = fused KV (o<384: k
// with pos+scale*log2e -> Yt; o>=384: v -> Y2 channel-major);  3 = f32+bias.
// ---------------------------------------------------------------------------
template<int EPI, bool CONV>
__global__ __launch_bounds__(256, 2) void mfma_gemm(
    const short* __restrict__ A, const short* __restrict__ Bm,
    short* __restrict__ Yt, short* __restrict__ Y2, float* __restrict__ Yf,
    const float* __restrict__ bias, const float* __restrict__ relh,
    const float* __restrict__ relw, int Ksz, int S)
{
    __shared__ short At[128 * 64];
    __shared__ short Bt[128 * 64];
    const int b = blockIdx.z, o0 = blockIdx.y * 128, s0 = blockIdx.x * 128;
    const int t = threadIdx.x, wave = t >> 6, lane = t & 63, g = lane >> 4, li = lane & 15;
    const int wr = wave >> 1, wc = wave & 1;
    floatx4 acc[4][4] = {};
    const short* Bbase = Bm + (size_t)b * S * Ksz;   // for CONV: == xT b-slab

    for (int k0 = 0; k0 < Ksz; k0 += 64) {
        __syncthreads();    // prior compute done reading buffers
        #pragma unroll
        for (int it = 0; it < 4; it++) {
            int task = it * 256 + t;
            int row = task >> 3, ch = task & 7;
            int cont = ch ^ (row & 7);
            g2lds16(A + (size_t)(o0 + row) * Ksz + k0 + cont * 8, At + task * 8);
        }
        #pragma unroll
        for (int it = 0; it < 4; it++) {
            int task = it * 256 + t;
            int row = task >> 3, ch = task & 7;
            int cont = ch ^ (row & 7);
            if constexpr (CONV) {
                int ssr = s0 + row;
                int hs = ssr >> 5, wsv = ssr & 31;
                int k = k0 + cont * 8;
                int p = k / 384, coff = k - p * 384;
                g2lds16(Bbase + (size_t)((2 * hs + (p >> 1)) * 64 + 2 * wsv + (p & 1)) * 384 + coff,
                        Bt + task * 8);
            } else {
                g2lds16(Bbase + (size_t)(s0 + row) * Ksz + k0 + cont * 8, Bt + task * 8);
            }
        }
        __syncthreads();    // implicit vmcnt(0) drains global_load_lds
        #pragma unroll
        for (int kk = 0; kk < 2; kk++) {
            b16x8 af[4], bf[4];
            #pragma unroll
            for (int mi = 0; mi < 4; mi++) {
                int r = wr * 64 + mi * 16 + li;
                af[mi] = *(const b16x8*)(At + r * 64 + (((kk * 4 + g) ^ (r & 7)) * 8));
            }
            #pragma unroll
            for (int nf = 0; nf < 4; nf++) {
                int r = wc * 64 + nf * 16 + li;
                bf[nf] = *(const b16x8*)(Bt + r * 64 + (((kk * 4 + g) ^ (r & 7)) * 8));
            }
            #pragma unroll
            for (int mi = 0; mi < 4; mi++)
                #pragma unroll
                for (int nf = 0; nf < 4; nf++)
                    acc[mi][nf] = __builtin_amdgcn_mfma_f32_16x16x32_bf16(af[mi], bf[nf], acc[mi][nf], 0, 0, 0);
        }
    }

    #pragma unroll
    for (int mi = 0; mi < 4; mi++) {
        #pragma unroll
        for (int nf = 0; nf < 4; nf++) {
            int o = o0 + wr * 64 + mi * 16 + g * 4;
            int s = s0 + wc * 64 + nf * 16 + li;
            if constexpr (EPI == 0 || EPI == 1) {
                b16x4 pk;
                #pragma unroll
                for (int j = 0; j < 4; j++) {
                    float v = acc[mi][nf][j];
                    if constexpr (EPI == 1) v += bias[o + j];
                    pk[j] = (short)f2bf(v);
                }
                *(b16x4*)(Yt + ((size_t)b * S + s) * CCH + o) = pk;
            } else if constexpr (EPI == 2) {
                if (o0 < 384) {
                    // pos[m] = rel_h[o][m & 31] + rel_w[o][m >> 5]
                    int hs = s >> 5, wsv = s & 31;
                    b16x4 pk;
                    #pragma unroll
                    for (int j = 0; j < 4; j++)
                        pk[j] = (short)f2bf((acc[mi][nf][j] + relh[(o + j) * 32 + wsv]
                                             + relw[(o + j) * 32 + hs]) * SCALE_L2E);
                    *(b16x4*)(Yt + ((size_t)b * S + s) * CCH + o) = pk;
                } else {
                    #pragma unroll
                    for (int j = 0; j < 4; j++)
                        Y2[((size_t)b * CCH + (o - 384 + j)) * NK + s] = (short)f2bf(acc[mi][nf][j]);
                }
            } else {
                #pragma unroll
                for (int j = 0; j < 4; j++)
                    Yf[((size_t)b * CCH + o + j) * (size_t)S + s] = acc[mi][nf][j] + bias[o + j];
            }
        }
    }
}

// ---------------------------------------------------------------------------
// Flash attention v5: LDS-staged K/V (chunk-major, conflict-free ds_read),
// K rows permuted at stage time (swap bits 2,3) so S^T slots align directly
// with the PV A-fragment -> ZERO cross-lane exchange.  l computed by the PV
// MFMA itself via a ones-row at V d=48.  s_setprio around MFMA clusters (T5).
// 32 q/wave, 128 q/block, 1024 blocks.
// ---------------------------------------------------------------------------
__global__ __launch_bounds__(256, 4) void attn_kern(
    const short* __restrict__ qT, const short* __restrict__ kT,
    const short* __restrict__ vC, short* __restrict__ attT)
{
    __shared__ short Kl[2][6 * 64 * 8];   // [buf][d-chunk 0..5][row][8]
    __shared__ short Vl[2][8 * 64 * 8];   // [buf][key-chunk 0..7][d-row][8]
    const int wgid = blockIdx.x;
    const int nid = (wgid & 7) * 128 + (wgid >> 3);    // XCD-chunked swizzle
    const int qt = nid & 31, hh = (nid >> 5) & 7, b = nid >> 8;
    const int t = threadIdx.x, wave = t >> 6, lane = t & 63;
    const int h = lane >> 5, c = lane & 31;
    const int n0 = qt * 128 + wave * 32;

    const short* qp = qT + (size_t)b * NQ * CCH + hh * HDIM;
    const short* kp = kT + (size_t)b * NK * CCH + hh * HDIM;
    const short* vp = vC + ((size_t)b * CCH + hh * HDIM) * NK;

    // init V pad rows 48..63 of every key-chunk: row 48 = 1.0 (l-column), rest 0
    {
        int bufi = t >> 7, rem = t & 127;          // 128 slots = 8 chunks x 16 rows
        int ch = rem >> 4, row = 48 + (rem & 15);
        b16x8 val = {};
        if (row == 48)
            #pragma unroll
            for (int e = 0; e < 8; e++) val[e] = (short)0x3F80;
        *(b16x8*)(&Vl[bufi][(ch * 64 + row) * 8]) = val;
    }

    // Q B-frags (persist): B[k=d][n=q], lane holds q=c, d = dc*16 + h*8 + e
    b16x8 qf[3];
    #pragma unroll
    for (int dc = 0; dc < 3; dc++)
        qf[dc] = *(const b16x8*)(qp + (size_t)(n0 + c) * CCH + dc * 16 + h * 8);

    // stage tile m0 -> buffer bi.  K: LDS row holds global key with bits 2,3
    // swapped (pre-permuted SOURCE, linear dest).  V: natural key columns.
    auto stage = [&](int m0, int bi) {
        #pragma unroll
        for (int it = 0; it < 2; it++) {
            int task = it * 256 + wave * 64 + lane;
            int ch = task >> 6, row = task & 63;
            if (ch < 6) {
                int key = (row & 51) | ((row & 4) << 1) | ((row & 8) >> 1);
                g2lds16(kp + (size_t)(m0 + key) * CCH + ch * 8, &Kl[bi][task * 8]);
            }
        }
        #pragma unroll
        for (int it = 0; it < 2; it++) {
            int task = it * 256 + wave * 64 + lane;
            int ch = task >> 6, row = task & 63;
            if (row < 48)
                g2lds16(vp + (size_t)row * NK + m0 + ch * 8, &Vl[bi][task * 8]);
        }
    };

    f32x16 O[2] = {};          // [dblock];  O[1] col c=16 accumulates l

    stage(0, 0);
    for (int tt = 0; tt < 16; ++tt) {
        __syncthreads();       // drains global_load_lds + joins waves
        if (tt < 15) stage((tt + 1) * 64, (tt + 1) & 1);
        const short* Kb = Kl[tt & 1];
        const short* Vb = Vl[tt & 1];
        #pragma unroll
        for (int kb = 0; kb < 2; kb++) {
            // K A-frags: chunk dc*2+h, row kb*32+c  (contiguous per half -> no conflicts)
            b16x8 kf[3];
            #pragma unroll
            for (int dc = 0; dc < 3; dc++)
                kf[dc] = *(const b16x8*)(Kb + (((dc * 2 + h) * 64) + kb * 32 + c) * 8);
            f32x16 s = {};
            __builtin_amdgcn_s_setprio(1);
            #pragma unroll
            for (int dc = 0; dc < 3; dc++)
                s = __builtin_amdgcn_mfma_f32_32x32x16_bf16(kf[dc], qf[dc], s, 0, 0, 0);
            __builtin_amdgcn_s_setprio(0);
            // slot r holds P[permuted key][q=c]; permutation aligns r=kk*8+e
            // with PV A-position (kk, h, e) -> pack pairs directly, no exchange
            float p[16];
            #pragma unroll
            for (int r = 0; r < 16; r++) p[r] = exp2f(s[r]);
            b16x8 pfrag[2];
            #pragma unroll
            for (int kk = 0; kk < 2; kk++) {
                union { unsigned u[4]; b16x8 v; } w;
                #pragma unroll
                for (int wd = 0; wd < 4; wd++)
                    w.u[wd] = pk2(p[kk * 8 + wd * 2], p[kk * 8 + wd * 2 + 1]);
                pfrag[kk] = w.v;
            }
            // PV: V B-frags: chunk kb*4+kk*2+h, row db*32+c (conflict-free)
            __builtin_amdgcn_s_setprio(1);
            #pragma unroll
            for (int kk = 0; kk < 2; kk++)
                #pragma unroll
                for (int db = 0; db < 2; db++) {
                    b16x8 vf = *(const b16x8*)(Vb + (((kb * 4 + kk * 2 + h) * 64) + db * 32 + c) * 8);
                    O[db] = __builtin_amdgcn_mfma_f32_32x32x16_bf16(pfrag[kk], vf, O[db], 0, 0, 0);
                }
            __builtin_amdgcn_s_setprio(0);
        }
    }

    __syncthreads();   // all waves done reading V before Olw overlays it
    // l[q-slot r] lives in lane (h, c=16) at O[1][r]; broadcast + normalize
    short* Olw = ((short*)Vl) + wave * 2048;
    #pragma unroll
    for (int r = 0; r < 16; r++) {
        int qrow = (r & 3) + 8 * (r >> 2) + 4 * h;
        float lr = __shfl(O[1][r], (lane & 32) | 16);
        float iq = 1.0f / lr;
        #pragma unroll
        for (int db = 0; db < 2; db++) {
            int d = db * 32 + c;
            if (d < 48)
                Olw[qrow * 64 + (((d >> 3) ^ (qrow & 7)) * 8) + (d & 7)] =
                    (short)f2bf(O[db][r] * iq);
        }
    }
    __syncthreads();
    #pragma unroll
    for (int it = 0; it < 4; it++) {
        int idx = it * 64 + lane;
        int row = idx >> 3, c8 = idx & 7;
        if (c8 < 6) {
            b16x8 val = *(const b16x8*)(Olw + row * 64 + ((c8 ^ (row & 7)) * 8));
            *(b16x8*)(attT + ((size_t)b * NQ + n0 + row) * CCH + hh * HDIM + c8 * 8) = val;
        }
    }
}

// ---------------------------------------------------------------------------
extern "C" void kernel_launch(void* const* d_in, const int* in_sizes, int n_in,
                              void* d_out, int out_size, void* d_ws, size_t ws_size,
                              hipStream_t stream) {
    const float* x    = (const float*)d_in[0];
    const float* Wq   = (const float*)d_in[1];
    const float* Wk   = (const float*)d_in[2];
    const float* Wv   = (const float*)d_in[3];
    const float* Wsr  = (const float*)d_in[4];
    const float* bsr  = (const float*)d_in[5];
    const float* Wp   = (const float*)d_in[6];
    const float* bp   = (const float*)d_in[7];
    const float* relh = (const float*)d_in[8];
    const float* relw = (const float*)d_in[9];
    float* out = (float*)d_out;

    short* ws = (short*)d_ws;
    size_t off = 0;
    auto alloc = [&](size_t n) { short* p = ws + off; off += n; return p; };
    short* WqB  = alloc(147456);
    short* WkvB = alloc(294912);
    short* WsrB = alloc(589824);
    short* WpB  = alloc(147456);
    short* xT   = alloc((size_t)BATCH * NQ * CCH);
    short* xsrT = alloc((size_t)BATCH * NK * CCH);
    short* qTb  = alloc((size_t)BATCH * NQ * CCH);
    short* kTb  = alloc((size_t)BATCH * NK * CCH);
    short* vCb  = alloc((size_t)BATCH * CCH * NK);
    short* attT = alloc((size_t)BATCH * NQ * CCH);

    cvt_all<<<dim3(576, 5), 256, 0, stream>>>(Wq, Wk, Wv, Wsr, Wp, WqB, WkvB, WsrB, WpB);
    t1_kern<<<dim3(64, 6, BATCH), 256, 0, stream>>>(x, xT);
    // SR conv as GEMM (+bsr), im2col gathered from xT, output xsrT[ssr][c]
    mfma_gemm<1, true><<<dim3(8, 3, BATCH), 256, 0, stream>>>(
        WsrB, xT, xsrT, nullptr, nullptr, bsr, nullptr, nullptr, 1536, NK);
    // Q projection -> qT[n][c]
    mfma_gemm<0, false><<<dim3(32, 3, BATCH), 256, 0, stream>>>(
        WqB, xT, qTb, nullptr, nullptr, nullptr, nullptr, nullptr, 384, NQ);
    // fused K (+pos, *SCALE*log2e) -> kT[m][c]  and  V -> vC[c][m]
    mfma_gemm<2, false><<<dim3(8, 6, BATCH), 256, 0, stream>>>(
        WkvB, xsrT, kTb, vCb, nullptr, nullptr, relh, relw, 384, NK);
    // attention (1024 blocks, XCD-swizzled, LDS-staged K/V)
    attn_kern<<<dim3(1024), 256, 0, stream>>>(qTb, kTb, vCb, attT);
    // output projection (+bp), f32 natural layout
    mfma_gemm<3, false><<<dim3(32, 3, BATCH), 256, 0, stream>>>(
        WpB, attT, nullptr, nullptr, out, bp, nullptr, nullptr, 384, NQ);
}

// Round 10
// 127.967 us; speedup vs baseline: 1.5030x; 1.0828x over previous
//
#include <hip/hip_runtime.h>
#include <hip/hip_bf16.h>
#include <math.h>

typedef __attribute__((ext_vector_type(8))) short b16x8;
typedef __attribute__((ext_vector_type(4))) short b16x4;
typedef __attribute__((ext_vector_type(4))) float floatx4;
typedef __attribute__((ext_vector_type(16))) float f32x16;

constexpr int BATCH = 4, CCH = 384, NQ = 4096, NHD = 8, HDIM = 48, NK = 1024;
constexpr float SCALE = 0.14433756729740643f;            // 48^-0.5
constexpr float SCALE_L2E = 0.14433756729740643f * 1.4426950408889634f; // *log2(e)

__device__ inline unsigned short f2bf(float f) {
    unsigned u = __builtin_bit_cast(unsigned, f);
    u += 0x7fffu + ((u >> 16) & 1u);
    return (unsigned short)(u >> 16);
}

__device__ __forceinline__ void g2lds16(const void* g, void* l) {
    __builtin_amdgcn_global_load_lds(
        (const __attribute__((address_space(1))) unsigned int*)g,
        (__attribute__((address_space(3))) unsigned int*)l, 16, 0, 0);
}

// ---------------------------------------------------------------------------
// Weight conversion fp32 -> bf16.  Wk,Wv stacked into WkvB[768][384].
// Wsr reordered to [o][pos*384+c]  (pos = i*2+j) so the conv-GEMM B operand
// becomes 4 contiguous xT row segments per 64-wide k chunk.
// ---------------------------------------------------------------------------
__global__ void cvt_all(const float* __restrict__ Wq, const float* __restrict__ Wk,
                        const float* __restrict__ Wv, const float* __restrict__ Wsr,
                        const float* __restrict__ Wp,
                        short* __restrict__ WqB, short* __restrict__ WkvB,
                        short* __restrict__ WsrB, short* __restrict__ WpB) {
    int job = blockIdx.y;
    if (job == 3) {
        for (int i = blockIdx.x * 256 + threadIdx.x; i < 589824; i += gridDim.x * 256) {
            int o = i / 1536, r = i - o * 1536;
            WsrB[o * 1536 + (r & 3) * 384 + (r >> 2)] = (short)f2bf(Wsr[i]);
        }
        return;
    }
    const float* src; short* dst;
    if (job == 0)      { src = Wq;  dst = WqB; }
    else if (job == 1) { src = Wk;  dst = WkvB; }
    else if (job == 2) { src = Wv;  dst = WkvB + 147456; }
    else               { src = Wp;  dst = WpB; }
    for (int i = blockIdx.x * 256 + threadIdx.x; i < 147456; i += gridDim.x * 256)
        dst[i] = (short)f2bf(src[i]);
}

// ---------------------------------------------------------------------------
// x [B][384][4096] f32  ->  xT [B][4096][384] bf16 (token-major)
// ---------------------------------------------------------------------------
__global__ void t1_kern(const float* __restrict__ x, short* __restrict__ xT) {
    int b = blockIdx.z, s = blockIdx.x * 64 + (threadIdx.x & 63);
    for (int c8 = blockIdx.y * 8 + (threadIdx.x >> 6); c8 < blockIdx.y * 8 + 8; c8 += 4) {
        b16x8 pk;
        #pragma unroll
        for (int e = 0; e < 8; e++)
            pk[e] = (short)f2bf(x[((size_t)b * CCH + c8 * 8 + e) * NQ + s]);
        *(b16x8*)(xT + ((size_t)b * NQ + s) * CCH + c8 * 8) = pk;
    }
}

// ---------------------------------------------------------------------------
// FUSED conv+Q GEMM, one dispatch to fill the GPU (480 blocks).
// Block id < 24 per batch: SR-conv as GEMM (im2col from xT, K=1536, +bsr)
//   -> xsrT[ssr][c].  Else: Q projection (K=384) -> qT[n][c].
// 128x128 tile, BK=64, global_load_lds staging (linear dest, inverse-XOR
// swizzled source), 4 waves x 4x4 frags of 16x16x32.
// ---------------------------------------------------------------------------
__global__ __launch_bounds__(256, 2) void fused_gemm1(
    const short* __restrict__ WsrB, const short* __restrict__ WqB,
    const short* __restrict__ xT, const float* __restrict__ bsr,
    short* __restrict__ xsrT, short* __restrict__ qTb)
{
    __shared__ short At[128 * 64];
    __shared__ short Bt[128 * 64];
    const int b = blockIdx.z;
    const int id = blockIdx.x;
    const bool conv = id < 24;
    const int sx = conv ? (id & 7) : ((id - 24) & 31);
    const int oy = conv ? (id >> 3) : ((id - 24) >> 5);
    const int Ks = conv ? 1536 : 384;
    const int S  = conv ? NK : NQ;
    const short* A = conv ? WsrB : WqB;
    short* Yt = conv ? xsrT : qTb;
    const int o0 = oy * 128, s0 = sx * 128;
    const int t = threadIdx.x, wave = t >> 6, lane = t & 63, g = lane >> 4, li = lane & 15;
    const int wr = wave >> 1, wc = wave & 1;
    floatx4 acc[4][4] = {};
    const short* Bbase = xT + (size_t)b * NQ * CCH;

    for (int k0 = 0; k0 < Ks; k0 += 64) {
        __syncthreads();
        #pragma unroll
        for (int it = 0; it < 4; it++) {
            int task = it * 256 + t;
            int row = task >> 3, ch = task & 7;
            int cont = ch ^ (row & 7);
            g2lds16(A + (size_t)(o0 + row) * Ks + k0 + cont * 8, At + task * 8);
        }
        #pragma unroll
        for (int it = 0; it < 4; it++) {
            int task = it * 256 + t;
            int row = task >> 3, ch = task & 7;
            int cont = ch ^ (row & 7);
            if (conv) {
                int ssr = s0 + row;
                int hs = ssr >> 5, wsv = ssr & 31;
                int k = k0 + cont * 8;
                int p = k / 384, coff = k - p * 384;
                g2lds16(Bbase + (size_t)((2 * hs + (p >> 1)) * 64 + 2 * wsv + (p & 1)) * 384 + coff,
                        Bt + task * 8);
            } else {
                g2lds16(Bbase + (size_t)(s0 + row) * 384 + k0 + cont * 8, Bt + task * 8);
            }
        }
        __syncthreads();
        #pragma unroll
        for (int kk = 0; kk < 2; kk++) {
            b16x8 af[4], bf[4];
            #pragma unroll
            for (int mi = 0; mi < 4; mi++) {
                int r = wr * 64 + mi * 16 + li;
                af[mi] = *(const b16x8*)(At + r * 64 + (((kk * 4 + g) ^ (r & 7)) * 8));
            }
            #pragma unroll
            for (int nf = 0; nf < 4; nf++) {
                int r = wc * 64 + nf * 16 + li;
                bf[nf] = *(const b16x8*)(Bt + r * 64 + (((kk * 4 + g) ^ (r & 7)) * 8));
            }
            #pragma unroll
            for (int mi = 0; mi < 4; mi++)
                #pragma unroll
                for (int nf = 0; nf < 4; nf++)
                    acc[mi][nf] = __builtin_amdgcn_mfma_f32_16x16x32_bf16(af[mi], bf[nf], acc[mi][nf], 0, 0, 0);
        }
    }

    #pragma unroll
    for (int mi = 0; mi < 4; mi++) {
        #pragma unroll
        for (int nf = 0; nf < 4; nf++) {
            int o = o0 + wr * 64 + mi * 16 + g * 4;
            int s = s0 + wc * 64 + nf * 16 + li;
            b16x4 pk;
            #pragma unroll
            for (int j = 0; j < 4; j++) {
                float v = acc[mi][nf][j];
                if (conv) v += bsr[o + j];
                pk[j] = (short)f2bf(v);
            }
            *(b16x4*)(Yt + ((size_t)b * S + s) * CCH + o) = pk;
        }
    }
}

// ---------------------------------------------------------------------------
// MFMA GEMM (KV and P projections): Y[o][s] = sum_k A[o][k] * B[b][s][k].
// EPI: 2 = fused KV (o<384: k with pos+scale*log2e -> Yt; o>=384: v -> Y2
// channel-major);  3 = f32 natural + bias.
// ---------------------------------------------------------------------------
template<int EPI>
__global__ __launch_bounds__(256, 2) void mfma_gemm(
    const short* __restrict__ A, const short* __restrict__ Bm,
    short* __restrict__ Yt, short* __restrict__ Y2, float* __restrict__ Yf,
    const float* __restrict__ bias, const float* __restrict__ relh,
    const float* __restrict__ relw, int Ksz, int S)
{
    __shared__ short At[128 * 64];
    __shared__ short Bt[128 * 64];
    const int b = blockIdx.z, o0 = blockIdx.y * 128, s0 = blockIdx.x * 128;
    const int t = threadIdx.x, wave = t >> 6, lane = t & 63, g = lane >> 4, li = lane & 15;
    const int wr = wave >> 1, wc = wave & 1;
    floatx4 acc[4][4] = {};
    const short* Bbase = Bm + (size_t)b * S * Ksz;

    for (int k0 = 0; k0 < Ksz; k0 += 64) {
        __syncthreads();
        #pragma unroll
        for (int it = 0; it < 4; it++) {
            int task = it * 256 + t;
            int row = task >> 3, ch = task & 7;
            int cont = ch ^ (row & 7);
            g2lds16(A + (size_t)(o0 + row) * Ksz + k0 + cont * 8, At + task * 8);
        }
        #pragma unroll
        for (int it = 0; it < 4; it++) {
            int task = it * 256 + t;
            int row = task >> 3, ch = task & 7;
            int cont = ch ^ (row & 7);
            g2lds16(Bbase + (size_t)(s0 + row) * Ksz + k0 + cont * 8, Bt + task * 8);
        }
        __syncthreads();
        #pragma unroll
        for (int kk = 0; kk < 2; kk++) {
            b16x8 af[4], bf[4];
            #pragma unroll
            for (int mi = 0; mi < 4; mi++) {
                int r = wr * 64 + mi * 16 + li;
                af[mi] = *(const b16x8*)(At + r * 64 + (((kk * 4 + g) ^ (r & 7)) * 8));
            }
            #pragma unroll
            for (int nf = 0; nf < 4; nf++) {
                int r = wc * 64 + nf * 16 + li;
                bf[nf] = *(const b16x8*)(Bt + r * 64 + (((kk * 4 + g) ^ (r & 7)) * 8));
            }
            #pragma unroll
            for (int mi = 0; mi < 4; mi++)
                #pragma unroll
                for (int nf = 0; nf < 4; nf++)
                    acc[mi][nf] = __builtin_amdgcn_mfma_f32_16x16x32_bf16(af[mi], bf[nf], acc[mi][nf], 0, 0, 0);
        }
    }

    #pragma unroll
    for (int mi = 0; mi < 4; mi++) {
        #pragma unroll
        for (int nf = 0; nf < 4; nf++) {
            int o = o0 + wr * 64 + mi * 16 + g * 4;
            int s = s0 + wc * 64 + nf * 16 + li;
            if constexpr (EPI == 2) {
                if (o0 < 384) {
                    // pos[m] = rel_h[o][m & 31] + rel_w[o][m >> 5]
                    int hs = s >> 5, wsv = s & 31;
                    b16x4 pk;
                    #pragma unroll
                    for (int j = 0; j < 4; j++)
                        pk[j] = (short)f2bf((acc[mi][nf][j] + relh[(o + j) * 32 + wsv]
                                             + relw[(o + j) * 32 + hs]) * SCALE_L2E);
                    *(b16x4*)(Yt + ((size_t)b * S + s) * CCH + o) = pk;
                } else {
                    #pragma unroll
                    for (int j = 0; j < 4; j++)
                        Y2[((size_t)b * CCH + (o - 384 + j)) * NK + s] = (short)f2bf(acc[mi][nf][j]);
                }
            } else {
                #pragma unroll
                for (int j = 0; j < 4; j++)
                    Yf[((size_t)b * CCH + o + j) * (size_t)S + s] = acc[mi][nf][j] + bias[o + j];
            }
        }
    }
}

// ---------------------------------------------------------------------------
// Flash attention v6: LDS-staged K/V (chunk-major, conflict-free ds_read),
// K rows permuted at stage time (swap bits 2,3) so S^T slots align directly
// with the PV A-fragment -> ZERO cross-lane exchange.  l via ones-row MFMA.
// P pack via v_cvt_pk_bf16_f32 (T12).  32 q/wave, 128 q/block, 1024 blocks.
// ---------------------------------------------------------------------------
__global__ __launch_bounds__(256, 4) void attn_kern(
    const short* __restrict__ qT, const short* __restrict__ kT,
    const short* __restrict__ vC, short* __restrict__ attT)
{
    __shared__ short Kl[2][6 * 64 * 8];   // [buf][d-chunk 0..5][row][8]
    __shared__ short Vl[2][8 * 64 * 8];   // [buf][key-chunk 0..7][d-row][8]
    const int wgid = blockIdx.x;
    const int nid = (wgid & 7) * 128 + (wgid >> 3);    // XCD-chunked swizzle
    const int qt = nid & 31, hh = (nid >> 5) & 7, b = nid >> 8;
    const int t = threadIdx.x, wave = t >> 6, lane = t & 63;
    const int h = lane >> 5, c = lane & 31;
    const int n0 = qt * 128 + wave * 32;

    const short* qp = qT + (size_t)b * NQ * CCH + hh * HDIM;
    const short* kp = kT + (size_t)b * NK * CCH + hh * HDIM;
    const short* vp = vC + ((size_t)b * CCH + hh * HDIM) * NK;

    // init V pad rows 48..63 of every key-chunk: row 48 = 1.0 (l-column), rest 0
    {
        int bufi = t >> 7, rem = t & 127;          // 128 slots = 8 chunks x 16 rows
        int ch = rem >> 4, row = 48 + (rem & 15);
        b16x8 val = {};
        if (row == 48)
            #pragma unroll
            for (int e = 0; e < 8; e++) val[e] = (short)0x3F80;
        *(b16x8*)(&Vl[bufi][(ch * 64 + row) * 8]) = val;
    }

    // Q B-frags (persist): B[k=d][n=q], lane holds q=c, d = dc*16 + h*8 + e
    b16x8 qf[3];
    #pragma unroll
    for (int dc = 0; dc < 3; dc++)
        qf[dc] = *(const b16x8*)(qp + (size_t)(n0 + c) * CCH + dc * 16 + h * 8);

    // stage tile m0 -> buffer bi.  K: LDS row holds global key with bits 2,3
    // swapped (pre-permuted SOURCE, linear dest).  V: natural key columns.
    auto stage = [&](int m0, int bi) {
        #pragma unroll
        for (int it = 0; it < 2; it++) {
            int task = it * 256 + wave * 64 + lane;
            int ch = task >> 6, row = task & 63;
            if (ch < 6) {
                int key = (row & 51) | ((row & 4) << 1) | ((row & 8) >> 1);
                g2lds16(kp + (size_t)(m0 + key) * CCH + ch * 8, &Kl[bi][task * 8]);
            }
        }
        #pragma unroll
        for (int it = 0; it < 2; it++) {
            int task = it * 256 + wave * 64 + lane;
            int ch = task >> 6, row = task & 63;
            if (row < 48)
                g2lds16(vp + (size_t)row * NK + m0 + ch * 8, &Vl[bi][task * 8]);
        }
    };

    f32x16 O[2] = {};          // [dblock];  O[1] col c=16 accumulates l

    stage(0, 0);
    for (int tt = 0; tt < 16; ++tt) {
        __syncthreads();       // drains global_load_lds + joins waves
        if (tt < 15) stage((tt + 1) * 64, (tt + 1) & 1);
        const short* Kb = Kl[tt & 1];
        const short* Vb = Vl[tt & 1];
        #pragma unroll
        for (int kb = 0; kb < 2; kb++) {
            // K A-frags: chunk dc*2+h, row kb*32+c  (contiguous per half -> no conflicts)
            b16x8 kf[3];
            #pragma unroll
            for (int dc = 0; dc < 3; dc++)
                kf[dc] = *(const b16x8*)(Kb + (((dc * 2 + h) * 64) + kb * 32 + c) * 8);
            f32x16 s = {};
            __builtin_amdgcn_s_setprio(1);
            #pragma unroll
            for (int dc = 0; dc < 3; dc++)
                s = __builtin_amdgcn_mfma_f32_32x32x16_bf16(kf[dc], qf[dc], s, 0, 0, 0);
            __builtin_amdgcn_s_setprio(0);
            // slot r holds P[permuted key][q=c]; permutation aligns r=kk*8+e
            // with PV A-position (kk, h, e) -> pack pairs directly, no exchange
            float p[16];
            #pragma unroll
            for (int r = 0; r < 16; r++) p[r] = exp2f(s[r]);
            b16x8 pfrag[2];
            #pragma unroll
            for (int kk = 0; kk < 2; kk++) {
                union { unsigned u[4]; b16x8 v; } w;
                #pragma unroll
                for (int wd = 0; wd < 4; wd++)
                    asm("v_cvt_pk_bf16_f32 %0, %1, %2"
                        : "=v"(w.u[wd])
                        : "v"(p[kk * 8 + wd * 2]), "v"(p[kk * 8 + wd * 2 + 1]));
                pfrag[kk] = w.v;
            }
            // PV: V B-frags: chunk kb*4+kk*2+h, row db*32+c (conflict-free)
            __builtin_amdgcn_s_setprio(1);
            #pragma unroll
            for (int kk = 0; kk < 2; kk++)
                #pragma unroll
                for (int db = 0; db < 2; db++) {
                    b16x8 vf = *(const b16x8*)(Vb + (((kb * 4 + kk * 2 + h) * 64) + db * 32 + c) * 8);
                    O[db] = __builtin_amdgcn_mfma_f32_32x32x16_bf16(pfrag[kk], vf, O[db], 0, 0, 0);
                }
            __builtin_amdgcn_s_setprio(0);
        }
    }

    __syncthreads();   // all waves done reading V before Olw overlays it
    // l[q-slot r] lives in lane (h, c=16) at O[1][r]; broadcast + normalize
    short* Olw = ((short*)Vl) + wave * 2048;
    #pragma unroll
    for (int r = 0; r < 16; r++) {
        int qrow = (r & 3) + 8 * (r >> 2) + 4 * h;
        float lr = __shfl(O[1][r], (lane & 32) | 16);
        float iq = 1.0f / lr;
        #pragma unroll
        for (int db = 0; db < 2; db++) {
            int d = db * 32 + c;
            if (d < 48)
                Olw[qrow * 64 + (((d >> 3) ^ (qrow & 7)) * 8) + (d & 7)] =
                    (short)f2bf(O[db][r] * iq);
        }
    }
    __syncthreads();
    #pragma unroll
    for (int it = 0; it < 4; it++) {
        int idx = it * 64 + lane;
        int row = idx >> 3, c8 = idx & 7;
        if (c8 < 6) {
            b16x8 val = *(const b16x8*)(Olw + row * 64 + ((c8 ^ (row & 7)) * 8));
            *(b16x8*)(attT + ((size_t)b * NQ + n0 + row) * CCH + hh * HDIM + c8 * 8) = val;
        }
    }
}

// ---------------------------------------------------------------------------
extern "C" void kernel_launch(void* const* d_in, const int* in_sizes, int n_in,
                              void* d_out, int out_size, void* d_ws, size_t ws_size,
                              hipStream_t stream) {
    const float* x    = (const float*)d_in[0];
    const float* Wq   = (const float*)d_in[1];
    const float* Wk   = (const float*)d_in[2];
    const float* Wv   = (const float*)d_in[3];
    const float* Wsr  = (const float*)d_in[4];
    const float* bsr  = (const float*)d_in[5];
    const float* Wp   = (const float*)d_in[6];
    const float* bp   = (const float*)d_in[7];
    const float* relh = (const float*)d_in[8];
    const float* relw = (const float*)d_in[9];
    float* out = (float*)d_out;

    short* ws = (short*)d_ws;
    size_t off = 0;
    auto alloc = [&](size_t n) { short* p = ws + off; off += n; return p; };
    short* WqB  = alloc(147456);
    short* WkvB = alloc(294912);
    short* WsrB = alloc(589824);
    short* WpB  = alloc(147456);
    short* xT   = alloc((size_t)BATCH * NQ * CCH);
    short* xsrT = alloc((size_t)BATCH * NK * CCH);
    short* qTb  = alloc((size_t)BATCH * NQ * CCH);
    short* kTb  = alloc((size_t)BATCH * NK * CCH);
    short* vCb  = alloc((size_t)BATCH * CCH * NK);
    short* attT = alloc((size_t)BATCH * NQ * CCH);

    cvt_all<<<dim3(576, 5), 256, 0, stream>>>(Wq, Wk, Wv, Wsr, Wp, WqB, WkvB, WsrB, WpB);
    t1_kern<<<dim3(64, 6, BATCH), 256, 0, stream>>>(x, xT);
    // fused SR-conv (+bsr) -> xsrT  AND  Q projection -> qT, one dispatch
    fused_gemm1<<<dim3(120, 1, BATCH), 256, 0, stream>>>(WsrB, WqB, xT, bsr, xsrT, qTb);
    // fused K (+pos, *SCALE*log2e) -> kT[m][c]  and  V -> vC[c][m]
    mfma_gemm<2><<<dim3(8, 6, BATCH), 256, 0, stream>>>(
        WkvB, xsrT, kTb, vCb, nullptr, nullptr, relh, relw, 384, NK);
    // attention (1024 blocks, XCD-swizzled, LDS-staged K/V)
    attn_kern<<<dim3(1024), 256, 0, stream>>>(qTb, kTb, vCb, attT);
    // output projection (+bp), f32 natural layout
    mfma_gemm<3><<<dim3(32, 3, BATCH), 256, 0, stream>>>(
        WpB, attT, nullptr, nullptr, out, bp, nullptr, nullptr, 384, NQ);
}

// Round 12
// 126.097 us; speedup vs baseline: 1.5253x; 1.0148x over previous
//
#include <hip/hip_runtime.h>
#include <hip/hip_bf16.h>
#include <math.h>

typedef __attribute__((ext_vector_type(8))) short b16x8;
typedef __attribute__((ext_vector_type(4))) short b16x4;
typedef __attribute__((ext_vector_type(4))) float floatx4;
typedef __attribute__((ext_vector_type(16))) float f32x16;

constexpr int BATCH = 4, CCH = 384, NQ = 4096, NHD = 8, HDIM = 48, NK = 1024;
constexpr float SCALE = 0.14433756729740643f;            // 48^-0.5
constexpr float SCALE_L2E = 0.14433756729740643f * 1.4426950408889634f; // *log2(e)

__device__ inline unsigned short f2bf(float f) {
    unsigned u = __builtin_bit_cast(unsigned, f);
    u += 0x7fffu + ((u >> 16) & 1u);
    return (unsigned short)(u >> 16);
}

__device__ __forceinline__ void g2lds16(const void* g, void* l) {
    __builtin_amdgcn_global_load_lds(
        (const __attribute__((address_space(1))) unsigned int*)g,
        (__attribute__((address_space(3))) unsigned int*)l, 16, 0, 0);
}

// ---------------------------------------------------------------------------
// Weight conversion fp32 -> bf16.  Wk,Wv stacked into WkvB[768][384].
// Wsr transposed to WsrT[kin=p*384+cin][o] (combine-GEMM A operand).
// job 5: kvbias[o2] = dot(Wkv_row[o2], bsr)  (fp32).
// ---------------------------------------------------------------------------
__global__ void cvt_all(const float* __restrict__ Wq, const float* __restrict__ Wk,
                        const float* __restrict__ Wv, const float* __restrict__ Wsr,
                        const float* __restrict__ Wp, const float* __restrict__ bsr,
                        short* __restrict__ WqB, short* __restrict__ WkvB,
                        short* __restrict__ WsrT, short* __restrict__ WpB,
                        float* __restrict__ kvb) {
    int job = blockIdx.y;
    if (job == 3) {   // WsrT[kin][o] = Wsr[o][cin*4+p],  kin = p*384+cin
        for (int j = blockIdx.x * 256 + threadIdx.x; j < 589824; j += gridDim.x * 256) {
            int kin = j / 384, o = j - kin * 384;
            int p = kin / 384, cin = kin - p * 384;
            WsrT[j] = (short)f2bf(Wsr[o * 1536 + cin * 4 + p]);
        }
        return;
    }
    if (job == 5) {
        int o2 = blockIdx.x * 256 + threadIdx.x;
        if (o2 < 768) {
            const float* wrow = (o2 < 384) ? (Wk + (size_t)o2 * 384)
                                           : (Wv + (size_t)(o2 - 384) * 384);
            float ssum = 0.f;
            for (int c = 0; c < 384; c++) ssum += wrow[c] * bsr[c];
            kvb[o2] = ssum;
        }
        return;
    }
    const float* src; short* dst;
    if (job == 0)      { src = Wq;  dst = WqB; }
    else if (job == 1) { src = Wk;  dst = WkvB; }
    else if (job == 2) { src = Wv;  dst = WkvB + 147456; }
    else               { src = Wp;  dst = WpB; }
    for (int i = blockIdx.x * 256 + threadIdx.x; i < 147456; i += gridDim.x * 256)
        dst[i] = (short)f2bf(src[i]);
}

// ---------------------------------------------------------------------------
// x [B][384][4096] f32  ->  xT [B][4096][384] bf16 (token-major)
// ---------------------------------------------------------------------------
__global__ void t1_kern(const float* __restrict__ x, short* __restrict__ xT) {
    int b = blockIdx.z, s = blockIdx.x * 64 + (threadIdx.x & 63);
    for (int c8 = blockIdx.y * 8 + (threadIdx.x >> 6); c8 < blockIdx.y * 8 + 8; c8 += 4) {
        b16x8 pk;
        #pragma unroll
        for (int e = 0; e < 8; e++)
            pk[e] = (short)f2bf(x[((size_t)b * CCH + c8 * 8 + e) * NQ + s]);
        *(b16x8*)(xT + ((size_t)b * NQ + s) * CCH + c8 * 8) = pk;
    }
}

// ---------------------------------------------------------------------------
// Combine GEMM (one-off): Wc[o2][kin] = sum_c Wkv[o2][c] * Wsr[c][kin-map].
// A = WsrT[1536][384], Bm = WkvB[768][384]; Y[o=kin][s=o2] stored TRANSPOSED
// at Wc[s*1536 + o].  Grid (768/128, 1536/128) = (6,12).
// ---------------------------------------------------------------------------
__global__ __launch_bounds__(256, 2) void combine_gemm(
    const short* __restrict__ WsrT, const short* __restrict__ WkvB,
    short* __restrict__ Wc)
{
    __shared__ short At[128 * 64];
    __shared__ short Bt[128 * 64];
    const int o0 = blockIdx.y * 128, s0 = blockIdx.x * 128;
    const int t = threadIdx.x, wave = t >> 6, lane = t & 63, g = lane >> 4, li = lane & 15;
    const int wr = wave >> 1, wc = wave & 1;
    floatx4 acc[4][4] = {};

    for (int k0 = 0; k0 < 384; k0 += 64) {
        __syncthreads();
        #pragma unroll
        for (int it = 0; it < 4; it++) {
            int task = it * 256 + t;
            int row = task >> 3, ch = task & 7;
            int cont = ch ^ (row & 7);
            g2lds16(WsrT + (size_t)(o0 + row) * 384 + k0 + cont * 8, At + task * 8);
        }
        #pragma unroll
        for (int it = 0; it < 4; it++) {
            int task = it * 256 + t;
            int row = task >> 3, ch = task & 7;
            int cont = ch ^ (row & 7);
            g2lds16(WkvB + (size_t)(s0 + row) * 384 + k0 + cont * 8, Bt + task * 8);
        }
        __syncthreads();
        #pragma unroll
        for (int kk = 0; kk < 2; kk++) {
            b16x8 af[4], bf[4];
            #pragma unroll
            for (int mi = 0; mi < 4; mi++) {
                int r = wr * 64 + mi * 16 + li;
                af[mi] = *(const b16x8*)(At + r * 64 + (((kk * 4 + g) ^ (r & 7)) * 8));
            }
            #pragma unroll
            for (int nf = 0; nf < 4; nf++) {
                int r = wc * 64 + nf * 16 + li;
                bf[nf] = *(const b16x8*)(Bt + r * 64 + (((kk * 4 + g) ^ (r & 7)) * 8));
            }
            #pragma unroll
            for (int mi = 0; mi < 4; mi++)
                #pragma unroll
                for (int nf = 0; nf < 4; nf++)
                    acc[mi][nf] = __builtin_amdgcn_mfma_f32_16x16x32_bf16(af[mi], bf[nf], acc[mi][nf], 0, 0, 0);
        }
    }

    #pragma unroll
    for (int mi = 0; mi < 4; mi++) {
        #pragma unroll
        for (int nf = 0; nf < 4; nf++) {
            int o = o0 + wr * 64 + mi * 16 + g * 4;
            int s = s0 + wc * 64 + nf * 16 + li;
            b16x4 pk;
            #pragma unroll
            for (int j = 0; j < 4; j++) pk[j] = (short)f2bf(acc[mi][nf][j]);
            *(b16x4*)(Wc + (size_t)s * 1536 + o) = pk;
        }
    }
}

// ---------------------------------------------------------------------------
// FUSED Q + KV GEMM, one dispatch (576 blocks).  id<96: Q (K=384, from xT)
// -> qT.  Else KV (K=1536, combined weights Wc, im2col from xT):
// o<384 -> k (+kvbias+pos, *SCALE*log2e) -> kT;  o>=384 -> v (+kvbias) -> vC.
// ---------------------------------------------------------------------------
__global__ __launch_bounds__(256, 2) void fused_qkv(
    const short* __restrict__ WqB, const short* __restrict__ Wc,
    const short* __restrict__ xT, const float* __restrict__ kvb,
    const float* __restrict__ relh, const float* __restrict__ relw,
    short* __restrict__ qTb, short* __restrict__ kTb, short* __restrict__ vCb)
{
    __shared__ short At[128 * 64];
    __shared__ short Bt[128 * 64];
    const int b = blockIdx.z;
    const int id = blockIdx.x;
    const bool kv = id >= 96;
    const int sx = kv ? ((id - 96) & 7) : (id & 31);
    const int oy = kv ? ((id - 96) >> 3) : (id >> 5);
    const int Ks = kv ? 1536 : 384;
    const short* A = kv ? Wc : WqB;
    const int o0 = oy * 128, s0 = sx * 128;
    const int t = threadIdx.x, wave = t >> 6, lane = t & 63, g = lane >> 4, li = lane & 15;
    const int wr = wave >> 1, wc = wave & 1;
    floatx4 acc[4][4] = {};
    const short* Bbase = xT + (size_t)b * NQ * CCH;

    for (int k0 = 0; k0 < Ks; k0 += 64) {
        __syncthreads();
        #pragma unroll
        for (int it = 0; it < 4; it++) {
            int task = it * 256 + t;
            int row = task >> 3, ch = task & 7;
            int cont = ch ^ (row & 7);
            g2lds16(A + (size_t)(o0 + row) * Ks + k0 + cont * 8, At + task * 8);
        }
        #pragma unroll
        for (int it = 0; it < 4; it++) {
            int task = it * 256 + t;
            int row = task >> 3, ch = task & 7;
            int cont = ch ^ (row & 7);
            if (kv) {
                int ssr = s0 + row;
                int hs = ssr >> 5, wsv = ssr & 31;
                int k = k0 + cont * 8;
                int p = k / 384, coff = k - p * 384;
                g2lds16(Bbase + (size_t)((2 * hs + (p >> 1)) * 64 + 2 * wsv + (p & 1)) * 384 + coff,
                        Bt + task * 8);
            } else {
                g2lds16(Bbase + (size_t)(s0 + row) * 384 + k0 + cont * 8, Bt + task * 8);
            }
        }
        __syncthreads();
        #pragma unroll
        for (int kk = 0; kk < 2; kk++) {
            b16x8 af[4], bf[4];
            #pragma unroll
            for (int mi = 0; mi < 4; mi++) {
                int r = wr * 64 + mi * 16 + li;
                af[mi] = *(const b16x8*)(At + r * 64 + (((kk * 4 + g) ^ (r & 7)) * 8));
            }
            #pragma unroll
            for (int nf = 0; nf < 4; nf++) {
                int r = wc * 64 + nf * 16 + li;
                bf[nf] = *(const b16x8*)(Bt + r * 64 + (((kk * 4 + g) ^ (r & 7)) * 8));
            }
            #pragma unroll
            for (int mi = 0; mi < 4; mi++)
                #pragma unroll
                for (int nf = 0; nf < 4; nf++)
                    acc[mi][nf] = __builtin_amdgcn_mfma_f32_16x16x32_bf16(af[mi], bf[nf], acc[mi][nf], 0, 0, 0);
        }
    }

    #pragma unroll
    for (int mi = 0; mi < 4; mi++) {
        #pragma unroll
        for (int nf = 0; nf < 4; nf++) {
            int o = o0 + wr * 64 + mi * 16 + g * 4;
            int s = s0 + wc * 64 + nf * 16 + li;
            if (!kv) {
                b16x4 pk;
                #pragma unroll
                for (int j = 0; j < 4; j++) pk[j] = (short)f2bf(acc[mi][nf][j]);
                *(b16x4*)(qTb + ((size_t)b * NQ + s) * CCH + o) = pk;
            } else if (o0 < 384) {
                // pos[m] = rel_h[o][m & 31] + rel_w[o][m >> 5]
                int hs = s >> 5, wsv = s & 31;
                b16x4 pk;
                #pragma unroll
                for (int j = 0; j < 4; j++)
                    pk[j] = (short)f2bf((acc[mi][nf][j] + kvb[o + j]
                                         + relh[(o + j) * 32 + wsv]
                                         + relw[(o + j) * 32 + hs]) * SCALE_L2E);
                *(b16x4*)(kTb + ((size_t)b * NK + s) * CCH + o) = pk;
            } else {
                #pragma unroll
                for (int j = 0; j < 4; j++)
                    vCb[((size_t)b * CCH + (o - 384 + j)) * NK + s] =
                        (short)f2bf(acc[mi][nf][j] + kvb[o + j]);
            }
        }
    }
}

// ---------------------------------------------------------------------------
// P projection GEMM: out[o][s] f32 = sum_k Wp[o][k] * attT[s][k] + bp[o].
// ---------------------------------------------------------------------------
__global__ __launch_bounds__(256, 2) void p_gemm(
    const short* __restrict__ A, const short* __restrict__ Bm,
    float* __restrict__ Yf, const float* __restrict__ bias)
{
    __shared__ short At[128 * 64];
    __shared__ short Bt[128 * 64];
    const int b = blockIdx.z, o0 = blockIdx.y * 128, s0 = blockIdx.x * 128;
    const int t = threadIdx.x, wave = t >> 6, lane = t & 63, g = lane >> 4, li = lane & 15;
    const int wr = wave >> 1, wc = wave & 1;
    floatx4 acc[4][4] = {};
    const short* Bbase = Bm + (size_t)b * NQ * CCH;

    for (int k0 = 0; k0 < 384; k0 += 64) {
        __syncthreads();
        #pragma unroll
        for (int it = 0; it < 4; it++) {
            int task = it * 256 + t;
            int row = task >> 3, ch = task & 7;
            int cont = ch ^ (row & 7);
            g2lds16(A + (size_t)(o0 + row) * 384 + k0 + cont * 8, At + task * 8);
        }
        #pragma unroll
        for (int it = 0; it < 4; it++) {
            int task = it * 256 + t;
            int row = task >> 3, ch = task & 7;
            int cont = ch ^ (row & 7);
            g2lds16(Bbase + (size_t)(s0 + row) * 384 + k0 + cont * 8, Bt + task * 8);
        }
        __syncthreads();
        #pragma unroll
        for (int kk = 0; kk < 2; kk++) {
            b16x8 af[4], bf[4];
            #pragma unroll
            for (int mi = 0; mi < 4; mi++) {
                int r = wr * 64 + mi * 16 + li;
                af[mi] = *(const b16x8*)(At + r * 64 + (((kk * 4 + g) ^ (r & 7)) * 8));
            }
            #pragma unroll
            for (int nf = 0; nf < 4; nf++) {
                int r = wc * 64 + nf * 16 + li;
                bf[nf] = *(const b16x8*)(Bt + r * 64 + (((kk * 4 + g) ^ (r & 7)) * 8));
            }
            #pragma unroll
            for (int mi = 0; mi < 4; mi++)
                #pragma unroll
                for (int nf = 0; nf < 4; nf++)
                    acc[mi][nf] = __builtin_amdgcn_mfma_f32_16x16x32_bf16(af[mi], bf[nf], acc[mi][nf], 0, 0, 0);
        }
    }

    #pragma unroll
    for (int mi = 0; mi < 4; mi++) {
        #pragma unroll
        for (int nf = 0; nf < 4; nf++) {
            int o = o0 + wr * 64 + mi * 16 + g * 4;
            int s = s0 + wc * 64 + nf * 16 + li;
            #pragma unroll
            for (int j = 0; j < 4; j++)
                Yf[((size_t)b * CCH + o + j) * (size_t)NQ + s] = acc[mi][nf][j] + bias[o + j];
        }
    }
}

// ---------------------------------------------------------------------------
// Flash attention v7b: LDS-staged K/V (chunk-major, conflict-free ds_read),
// K rows permuted at stage time (swap bits 2,3) -> zero cross-lane exchange.
// l via ones-row MFMA.  P pack via v_cvt_pk_bf16_f32; exp via
// __builtin_amdgcn_exp2f (compiler-managed TRANS hazards — the round-11
// inline-asm v_exp_f32 lacked the required wait states).
// 32 q/wave, 128 q/block, 1024 blocks.
// ---------------------------------------------------------------------------
__global__ __launch_bounds__(256, 4) void attn_kern(
    const short* __restrict__ qT, const short* __restrict__ kT,
    const short* __restrict__ vC, short* __restrict__ attT)
{
    __shared__ short Kl[2][6 * 64 * 8];   // [buf][d-chunk 0..5][row][8]
    __shared__ short Vl[2][8 * 64 * 8];   // [buf][key-chunk 0..7][d-row][8]
    const int wgid = blockIdx.x;
    const int nid = (wgid & 7) * 128 + (wgid >> 3);    // XCD-chunked swizzle
    const int qt = nid & 31, hh = (nid >> 5) & 7, b = nid >> 8;
    const int t = threadIdx.x, wave = t >> 6, lane = t & 63;
    const int h = lane >> 5, c = lane & 31;
    const int n0 = qt * 128 + wave * 32;

    const short* qp = qT + (size_t)b * NQ * CCH + hh * HDIM;
    const short* kp = kT + (size_t)b * NK * CCH + hh * HDIM;
    const short* vp = vC + ((size_t)b * CCH + hh * HDIM) * NK;

    // init V pad rows 48..63 of every key-chunk: row 48 = 1.0 (l-column), rest 0
    {
        int bufi = t >> 7, rem = t & 127;          // 128 slots = 8 chunks x 16 rows
        int ch = rem >> 4, row = 48 + (rem & 15);
        b16x8 val = {};
        if (row == 48)
            #pragma unroll
            for (int e = 0; e < 8; e++) val[e] = (short)0x3F80;
        *(b16x8*)(&Vl[bufi][(ch * 64 + row) * 8]) = val;
    }

    // Q B-frags (persist): B[k=d][n=q], lane holds q=c, d = dc*16 + h*8 + e
    b16x8 qf[3];
    #pragma unroll
    for (int dc = 0; dc < 3; dc++)
        qf[dc] = *(const b16x8*)(qp + (size_t)(n0 + c) * CCH + dc * 16 + h * 8);

    // stage tile m0 -> buffer bi.  K: LDS row holds global key with bits 2,3
    // swapped (pre-permuted SOURCE, linear dest).  V: natural key columns.
    auto stage = [&](int m0, int bi) {
        #pragma unroll
        for (int it = 0; it < 2; it++) {
            int task = it * 256 + wave * 64 + lane;
            int ch = task >> 6, row = task & 63;
            if (ch < 6) {
                int key = (row & 51) | ((row & 4) << 1) | ((row & 8) >> 1);
                g2lds16(kp + (size_t)(m0 + key) * CCH + ch * 8, &Kl[bi][task * 8]);
            }
        }
        #pragma unroll
        for (int it = 0; it < 2; it++) {
            int task = it * 256 + wave * 64 + lane;
            int ch = task >> 6, row = task & 63;
            if (row < 48)
                g2lds16(vp + (size_t)row * NK + m0 + ch * 8, &Vl[bi][task * 8]);
        }
    };

    f32x16 O[2] = {};          // [dblock];  O[1] col c=16 accumulates l

    stage(0, 0);
    for (int tt = 0; tt < 16; ++tt) {
        __syncthreads();       // drains global_load_lds + joins waves
        if (tt < 15) stage((tt + 1) * 64, (tt + 1) & 1);
        const short* Kb = Kl[tt & 1];
        const short* Vb = Vl[tt & 1];
        #pragma unroll
        for (int kb = 0; kb < 2; kb++) {
            // K A-frags: chunk dc*2+h, row kb*32+c  (contiguous per half -> no conflicts)
            b16x8 kf[3];
            #pragma unroll
            for (int dc = 0; dc < 3; dc++)
                kf[dc] = *(const b16x8*)(Kb + (((dc * 2 + h) * 64) + kb * 32 + c) * 8);
            f32x16 s = {};
            __builtin_amdgcn_s_setprio(1);
            #pragma unroll
            for (int dc = 0; dc < 3; dc++)
                s = __builtin_amdgcn_mfma_f32_32x32x16_bf16(kf[dc], qf[dc], s, 0, 0, 0);
            __builtin_amdgcn_s_setprio(0);
            // slot r holds P[permuted key][q=c]; permutation aligns r=kk*8+e
            // with PV A-position (kk, h, e) -> pack pairs directly, no exchange
            float p[16];
            #pragma unroll
            for (int r = 0; r < 16; r++)
                p[r] = __builtin_amdgcn_exp2f(s[r]);   // v_exp_f32, hazards handled
            b16x8 pfrag[2];
            #pragma unroll
            for (int kk = 0; kk < 2; kk++) {
                union { unsigned u[4]; b16x8 v; } w;
                #pragma unroll
                for (int wd = 0; wd < 4; wd++)
                    asm("v_cvt_pk_bf16_f32 %0, %1, %2"
                        : "=v"(w.u[wd])
                        : "v"(p[kk * 8 + wd * 2]), "v"(p[kk * 8 + wd * 2 + 1]));
                pfrag[kk] = w.v;
            }
            // PV: V B-frags: chunk kb*4+kk*2+h, row db*32+c (conflict-free)
            __builtin_amdgcn_s_setprio(1);
            #pragma unroll
            for (int kk = 0; kk < 2; kk++)
                #pragma unroll
                for (int db = 0; db < 2; db++) {
                    b16x8 vf = *(const b16x8*)(Vb + (((kb * 4 + kk * 2 + h) * 64) + db * 32 + c) * 8);
                    O[db] = __builtin_amdgcn_mfma_f32_32x32x16_bf16(pfrag[kk], vf, O[db], 0, 0, 0);
                }
            __builtin_amdgcn_s_setprio(0);
        }
    }

    __syncthreads();   // all waves done reading V before Olw overlays it
    // l[q-slot r] lives in lane (h, c=16) at O[1][r]; broadcast + normalize
    short* Olw = ((short*)Vl) + wave * 2048;
    #pragma unroll
    for (int r = 0; r < 16; r++) {
        int qrow = (r & 3) + 8 * (r >> 2) + 4 * h;
        float lr = __shfl(O[1][r], (lane & 32) | 16);
        float iq = 1.0f / lr;
        #pragma unroll
        for (int db = 0; db < 2; db++) {
            int d = db * 32 + c;
            if (d < 48)
                Olw[qrow * 64 + (((d >> 3) ^ (qrow & 7)) * 8) + (d & 7)] =
                    (short)f2bf(O[db][r] * iq);
        }
    }
    __syncthreads();
    #pragma unroll
    for (int it = 0; it < 4; it++) {
        int idx = it * 64 + lane;
        int row = idx >> 3, c8 = idx & 7;
        if (c8 < 6) {
            b16x8 val = *(const b16x8*)(Olw + row * 64 + ((c8 ^ (row & 7)) * 8));
            *(b16x8*)(attT + ((size_t)b * NQ + n0 + row) * CCH + hh * HDIM + c8 * 8) = val;
        }
    }
}

// ---------------------------------------------------------------------------
extern "C" void kernel_launch(void* const* d_in, const int* in_sizes, int n_in,
                              void* d_out, int out_size, void* d_ws, size_t ws_size,
                              hipStream_t stream) {
    const float* x    = (const float*)d_in[0];
    const float* Wq   = (const float*)d_in[1];
    const float* Wk   = (const float*)d_in[2];
    const float* Wv   = (const float*)d_in[3];
    const float* Wsr  = (const float*)d_in[4];
    const float* bsr  = (const float*)d_in[5];
    const float* Wp   = (const float*)d_in[6];
    const float* bp   = (const float*)d_in[7];
    const float* relh = (const float*)d_in[8];
    const float* relw = (const float*)d_in[9];
    float* out = (float*)d_out;

    short* ws = (short*)d_ws;
    size_t off = 0;
    auto alloc = [&](size_t n) { short* p = ws + off; off += n; return p; };
    short* WqB  = alloc(147456);
    short* WkvB = alloc(294912);
    short* WsrT = alloc(589824);
    short* WpB  = alloc(147456);
    short* WcB  = alloc(768 * 1536);
    short* kvbh = alloc(768 * 2);         // fp32 kvbias (768 floats)
    short* xT   = alloc((size_t)BATCH * NQ * CCH);
    short* qTb  = alloc((size_t)BATCH * NQ * CCH);
    short* kTb  = alloc((size_t)BATCH * NK * CCH);
    short* vCb  = alloc((size_t)BATCH * CCH * NK);
    short* attT = alloc((size_t)BATCH * NQ * CCH);
    float* kvb  = (float*)kvbh;

    cvt_all<<<dim3(576, 6), 256, 0, stream>>>(Wq, Wk, Wv, Wsr, Wp, bsr,
                                              WqB, WkvB, WsrT, WpB, kvb);
    // Wc = Wkv @ Wsr  (combined conv+projection weights)
    combine_gemm<<<dim3(6, 12), 256, 0, stream>>>(WsrT, WkvB, WcB);
    t1_kern<<<dim3(64, 6, BATCH), 256, 0, stream>>>(x, xT);
    // fused Q -> qT  AND  KV direct from x (im2col, +kvbias, k: +pos *scale)
    fused_qkv<<<dim3(144, 1, BATCH), 256, 0, stream>>>(
        WqB, WcB, xT, kvb, relh, relw, qTb, kTb, vCb);
    // attention (1024 blocks, XCD-swizzled, LDS-staged K/V)
    attn_kern<<<dim3(1024), 256, 0, stream>>>(qTb, kTb, vCb, attT);
    // output projection (+bp), f32 natural layout
    p_gemm<<<dim3(32, 3, BATCH), 256, 0, stream>>>(WpB, attT, out, bp);
}

// Round 13
// 122.585 us; speedup vs baseline: 1.5690x; 1.0287x over previous
//
#include <hip/hip_runtime.h>
#include <hip/hip_bf16.h>
#include <math.h>

typedef __attribute__((ext_vector_type(8))) short b16x8;
typedef __attribute__((ext_vector_type(4))) short b16x4;
typedef __attribute__((ext_vector_type(4))) float floatx4;
typedef __attribute__((ext_vector_type(16))) float f32x16;

constexpr int BATCH = 4, CCH = 384, NQ = 4096, NHD = 8, HDIM = 48, NK = 1024;
constexpr float SCALE = 0.14433756729740643f;            // 48^-0.5
constexpr float SCALE_L2E = 0.14433756729740643f * 1.4426950408889634f; // *log2(e)

__device__ inline unsigned short f2bf(float f) {
    unsigned u = __builtin_bit_cast(unsigned, f);
    u += 0x7fffu + ((u >> 16) & 1u);
    return (unsigned short)(u >> 16);
}

__device__ __forceinline__ void g2lds16(const void* g, void* l) {
    __builtin_amdgcn_global_load_lds(
        (const __attribute__((address_space(1))) unsigned int*)g,
        (__attribute__((address_space(3))) unsigned int*)l, 16, 0, 0);
}

// ---------------------------------------------------------------------------
// PREP: weight cvt fp32->bf16 (jobs 0-5, as before) + x transpose (job 6).
// Wk,Wv stacked into WkvB[768][384].  WsrT[kin=p*384+cin][o] for combine.
// job 5: kvbias[o2] = dot(Wkv_row[o2], bsr).  job 6: xT[b][s][c] bf16.
// ---------------------------------------------------------------------------
__global__ void prep_kern(const float* __restrict__ Wq, const float* __restrict__ Wk,
                          const float* __restrict__ Wv, const float* __restrict__ Wsr,
                          const float* __restrict__ Wp, const float* __restrict__ bsr,
                          const float* __restrict__ x,
                          short* __restrict__ WqB, short* __restrict__ WkvB,
                          short* __restrict__ WsrT, short* __restrict__ WpB,
                          float* __restrict__ kvb, short* __restrict__ xT) {
    int job = blockIdx.y;
    if (job == 6) {   // x [B][384][4096] f32 -> xT [B][4096][384] bf16
        for (int i = blockIdx.x * 256 + threadIdx.x; i < BATCH * 4096 * 48;
             i += 576 * 256) {
            int b = i / (4096 * 48);
            int rem = i - b * (4096 * 48);
            int c8 = rem / 4096, s = rem - c8 * 4096;
            b16x8 pk;
            #pragma unroll
            for (int e = 0; e < 8; e++)
                pk[e] = (short)f2bf(x[((size_t)b * CCH + c8 * 8 + e) * NQ + s]);
            *(b16x8*)(xT + ((size_t)b * NQ + s) * CCH + c8 * 8) = pk;
        }
        return;
    }
    if (job == 3) {   // WsrT[kin][o] = Wsr[o][cin*4+p],  kin = p*384+cin
        for (int j = blockIdx.x * 256 + threadIdx.x; j < 589824; j += gridDim.x * 256) {
            int kin = j / 384, o = j - kin * 384;
            int p = kin / 384, cin = kin - p * 384;
            WsrT[j] = (short)f2bf(Wsr[o * 1536 + cin * 4 + p]);
        }
        return;
    }
    if (job == 5) {
        int o2 = blockIdx.x * 256 + threadIdx.x;
        if (o2 < 768) {
            const float* wrow = (o2 < 384) ? (Wk + (size_t)o2 * 384)
                                           : (Wv + (size_t)(o2 - 384) * 384);
            float ssum = 0.f;
            for (int c = 0; c < 384; c++) ssum += wrow[c] * bsr[c];
            kvb[o2] = ssum;
        }
        return;
    }
    const float* src; short* dst;
    if (job == 0)      { src = Wq;  dst = WqB; }
    else if (job == 1) { src = Wk;  dst = WkvB; }
    else if (job == 2) { src = Wv;  dst = WkvB + 147456; }
    else               { src = Wp;  dst = WpB; }
    for (int i = blockIdx.x * 256 + threadIdx.x; i < 147456; i += gridDim.x * 256)
        dst[i] = (short)f2bf(src[i]);
}

// ---------------------------------------------------------------------------
// Combine GEMM (one-off): Wc[o2][kin] = sum_c Wkv[o2][c] * Wsr[c][kin-map].
// A = WsrT[1536][384], Bm = WkvB[768][384]; stored transposed Wc[s*1536+o].
// ---------------------------------------------------------------------------
__global__ __launch_bounds__(256, 2) void combine_gemm(
    const short* __restrict__ WsrT, const short* __restrict__ WkvB,
    short* __restrict__ Wc)
{
    __shared__ short At[128 * 64];
    __shared__ short Bt[128 * 64];
    const int o0 = blockIdx.y * 128, s0 = blockIdx.x * 128;
    const int t = threadIdx.x, wave = t >> 6, lane = t & 63, g = lane >> 4, li = lane & 15;
    const int wr = wave >> 1, wc = wave & 1;
    floatx4 acc[4][4] = {};

    for (int k0 = 0; k0 < 384; k0 += 64) {
        __syncthreads();
        #pragma unroll
        for (int it = 0; it < 4; it++) {
            int task = it * 256 + t;
            int row = task >> 3, ch = task & 7;
            int cont = ch ^ (row & 7);
            g2lds16(WsrT + (size_t)(o0 + row) * 384 + k0 + cont * 8, At + task * 8);
        }
        #pragma unroll
        for (int it = 0; it < 4; it++) {
            int task = it * 256 + t;
            int row = task >> 3, ch = task & 7;
            int cont = ch ^ (row & 7);
            g2lds16(WkvB + (size_t)(s0 + row) * 384 + k0 + cont * 8, Bt + task * 8);
        }
        __syncthreads();
        #pragma unroll
        for (int kk = 0; kk < 2; kk++) {
            b16x8 af[4], bf[4];
            #pragma unroll
            for (int mi = 0; mi < 4; mi++) {
                int r = wr * 64 + mi * 16 + li;
                af[mi] = *(const b16x8*)(At + r * 64 + (((kk * 4 + g) ^ (r & 7)) * 8));
            }
            #pragma unroll
            for (int nf = 0; nf < 4; nf++) {
                int r = wc * 64 + nf * 16 + li;
                bf[nf] = *(const b16x8*)(Bt + r * 64 + (((kk * 4 + g) ^ (r & 7)) * 8));
            }
            #pragma unroll
            for (int mi = 0; mi < 4; mi++)
                #pragma unroll
                for (int nf = 0; nf < 4; nf++)
                    acc[mi][nf] = __builtin_amdgcn_mfma_f32_16x16x32_bf16(af[mi], bf[nf], acc[mi][nf], 0, 0, 0);
        }
    }

    #pragma unroll
    for (int mi = 0; mi < 4; mi++) {
        #pragma unroll
        for (int nf = 0; nf < 4; nf++) {
            int o = o0 + wr * 64 + mi * 16 + g * 4;
            int s = s0 + wc * 64 + nf * 16 + li;
            b16x4 pk;
            #pragma unroll
            for (int j = 0; j < 4; j++) pk[j] = (short)f2bf(acc[mi][nf][j]);
            *(b16x4*)(Wc + (size_t)s * 1536 + o) = pk;
        }
    }
}

// ---------------------------------------------------------------------------
// FUSED Q + KV GEMM, one dispatch.  id<96: Q (K=384, xT) -> qT.  Else KV
// (K=1536, combined Wc, im2col from xT): o<384 -> k (+kvb+pos, *scale) -> kT;
// o>=384 -> v (+kvb) -> vC channel-major.
// ---------------------------------------------------------------------------
__global__ __launch_bounds__(256, 2) void fused_qkv(
    const short* __restrict__ WqB, const short* __restrict__ Wc,
    const short* __restrict__ xT, const float* __restrict__ kvb,
    const float* __restrict__ relh, const float* __restrict__ relw,
    short* __restrict__ qTb, short* __restrict__ kTb, short* __restrict__ vCb)
{
    __shared__ short At[128 * 64];
    __shared__ short Bt[128 * 64];
    const int b = blockIdx.z;
    const int id = blockIdx.x;
    const bool kv = id >= 96;
    const int sx = kv ? ((id - 96) & 7) : (id & 31);
    const int oy = kv ? ((id - 96) >> 3) : (id >> 5);
    const int Ks = kv ? 1536 : 384;
    const short* A = kv ? Wc : WqB;
    const int o0 = oy * 128, s0 = sx * 128;
    const int t = threadIdx.x, wave = t >> 6, lane = t & 63, g = lane >> 4, li = lane & 15;
    const int wr = wave >> 1, wc = wave & 1;
    floatx4 acc[4][4] = {};
    const short* Bbase = xT + (size_t)b * NQ * CCH;

    for (int k0 = 0; k0 < Ks; k0 += 64) {
        __syncthreads();
        #pragma unroll
        for (int it = 0; it < 4; it++) {
            int task = it * 256 + t;
            int row = task >> 3, ch = task & 7;
            int cont = ch ^ (row & 7);
            g2lds16(A + (size_t)(o0 + row) * Ks + k0 + cont * 8, At + task * 8);
        }
        #pragma unroll
        for (int it = 0; it < 4; it++) {
            int task = it * 256 + t;
            int row = task >> 3, ch = task & 7;
            int cont = ch ^ (row & 7);
            if (kv) {
                int ssr = s0 + row;
                int hs = ssr >> 5, wsv = ssr & 31;
                int k = k0 + cont * 8;
                int p = k / 384, coff = k - p * 384;
                g2lds16(Bbase + (size_t)((2 * hs + (p >> 1)) * 64 + 2 * wsv + (p & 1)) * 384 + coff,
                        Bt + task * 8);
            } else {
                g2lds16(Bbase + (size_t)(s0 + row) * 384 + k0 + cont * 8, Bt + task * 8);
            }
        }
        __syncthreads();
        #pragma unroll
        for (int kk = 0; kk < 2; kk++) {
            b16x8 af[4], bf[4];
            #pragma unroll
            for (int mi = 0; mi < 4; mi++) {
                int r = wr * 64 + mi * 16 + li;
                af[mi] = *(const b16x8*)(At + r * 64 + (((kk * 4 + g) ^ (r & 7)) * 8));
            }
            #pragma unroll
            for (int nf = 0; nf < 4; nf++) {
                int r = wc * 64 + nf * 16 + li;
                bf[nf] = *(const b16x8*)(Bt + r * 64 + (((kk * 4 + g) ^ (r & 7)) * 8));
            }
            #pragma unroll
            for (int mi = 0; mi < 4; mi++)
                #pragma unroll
                for (int nf = 0; nf < 4; nf++)
                    acc[mi][nf] = __builtin_amdgcn_mfma_f32_16x16x32_bf16(af[mi], bf[nf], acc[mi][nf], 0, 0, 0);
        }
    }

    #pragma unroll
    for (int mi = 0; mi < 4; mi++) {
        #pragma unroll
        for (int nf = 0; nf < 4; nf++) {
            int o = o0 + wr * 64 + mi * 16 + g * 4;
            int s = s0 + wc * 64 + nf * 16 + li;
            if (!kv) {
                b16x4 pk;
                #pragma unroll
                for (int j = 0; j < 4; j++) pk[j] = (short)f2bf(acc[mi][nf][j]);
                *(b16x4*)(qTb + ((size_t)b * NQ + s) * CCH + o) = pk;
            } else if (o0 < 384) {
                // pos[m] = rel_h[o][m & 31] + rel_w[o][m >> 5]
                int hs = s >> 5, wsv = s & 31;
                b16x4 pk;
                #pragma unroll
                for (int j = 0; j < 4; j++)
                    pk[j] = (short)f2bf((acc[mi][nf][j] + kvb[o + j]
                                         + relh[(o + j) * 32 + wsv]
                                         + relw[(o + j) * 32 + hs]) * SCALE_L2E);
                *(b16x4*)(kTb + ((size_t)b * NK + s) * CCH + o) = pk;
            } else {
                #pragma unroll
                for (int j = 0; j < 4; j++)
                    vCb[((size_t)b * CCH + (o - 384 + j)) * NK + s] =
                        (short)f2bf(acc[mi][nf][j] + kvb[o + j]);
            }
        }
    }
}

// ---------------------------------------------------------------------------
// P projection GEMM: out[o][s] f32 = sum_k Wp[o][k] * attT[s][k] + bp[o].
// ---------------------------------------------------------------------------
__global__ __launch_bounds__(256, 2) void p_gemm(
    const short* __restrict__ A, const short* __restrict__ Bm,
    float* __restrict__ Yf, const float* __restrict__ bias)
{
    __shared__ short At[128 * 64];
    __shared__ short Bt[128 * 64];
    const int b = blockIdx.z, o0 = blockIdx.y * 128, s0 = blockIdx.x * 128;
    const int t = threadIdx.x, wave = t >> 6, lane = t & 63, g = lane >> 4, li = lane & 15;
    const int wr = wave >> 1, wc = wave & 1;
    floatx4 acc[4][4] = {};
    const short* Bbase = Bm + (size_t)b * NQ * CCH;

    for (int k0 = 0; k0 < 384; k0 += 64) {
        __syncthreads();
        #pragma unroll
        for (int it = 0; it < 4; it++) {
            int task = it * 256 + t;
            int row = task >> 3, ch = task & 7;
            int cont = ch ^ (row & 7);
            g2lds16(A + (size_t)(o0 + row) * 384 + k0 + cont * 8, At + task * 8);
        }
        #pragma unroll
        for (int it = 0; it < 4; it++) {
            int task = it * 256 + t;
            int row = task >> 3, ch = task & 7;
            int cont = ch ^ (row & 7);
            g2lds16(Bbase + (size_t)(s0 + row) * 384 + k0 + cont * 8, Bt + task * 8);
        }
        __syncthreads();
        #pragma unroll
        for (int kk = 0; kk < 2; kk++) {
            b16x8 af[4], bf[4];
            #pragma unroll
            for (int mi = 0; mi < 4; mi++) {
                int r = wr * 64 + mi * 16 + li;
                af[mi] = *(const b16x8*)(At + r * 64 + (((kk * 4 + g) ^ (r & 7)) * 8));
            }
            #pragma unroll
            for (int nf = 0; nf < 4; nf++) {
                int r = wc * 64 + nf * 16 + li;
                bf[nf] = *(const b16x8*)(Bt + r * 64 + (((kk * 4 + g) ^ (r & 7)) * 8));
            }
            #pragma unroll
            for (int mi = 0; mi < 4; mi++)
                #pragma unroll
                for (int nf = 0; nf < 4; nf++)
                    acc[mi][nf] = __builtin_amdgcn_mfma_f32_16x16x32_bf16(af[mi], bf[nf], acc[mi][nf], 0, 0, 0);
        }
    }

    #pragma unroll
    for (int mi = 0; mi < 4; mi++) {
        #pragma unroll
        for (int nf = 0; nf < 4; nf++) {
            int o = o0 + wr * 64 + mi * 16 + g * 4;
            int s = s0 + wc * 64 + nf * 16 + li;
            #pragma unroll
            for (int j = 0; j < 4; j++)
                Yf[((size_t)b * CCH + o + j) * (size_t)NQ + s] = acc[mi][nf][j] + bias[o + j];
        }
    }
}

// ---------------------------------------------------------------------------
// Flash attention v8: QBLK 64/wave (2 q-sub-blocks), 256 q/block, 512 blocks.
// LDS-staged K/V (chunk-major, conflict-free), K rows bit-2/3-swap permuted
// at stage time -> zero cross-lane exchange; l via ones-row MFMA; exp2
// builtin; cvt_pk pack.  Staging source offsets hoisted (tile-invariant).
// ---------------------------------------------------------------------------
__global__ __launch_bounds__(256, 2) void attn_kern(
    const short* __restrict__ qT, const short* __restrict__ kT,
    const short* __restrict__ vC, short* __restrict__ attT)
{
    __shared__ short Kl[2][6 * 64 * 8];   // [buf][d-chunk 0..5][row][8]
    __shared__ short Vl[2][8 * 64 * 8];   // [buf][key-chunk 0..7][d-row][8]
    const int wgid = blockIdx.x;
    const int nid = (wgid & 7) * 64 + (wgid >> 3);     // XCD swizzle (512 = 8*64)
    const int qt = nid & 15, hh = (nid >> 4) & 7, b = nid >> 7;
    const int t = threadIdx.x, wave = t >> 6, lane = t & 63;
    const int h = lane >> 5, c = lane & 31;
    const int n0 = qt * 256 + wave * 64;

    const short* qp = qT + (size_t)b * NQ * CCH + hh * HDIM;
    const short* kp = kT + (size_t)b * NK * CCH + hh * HDIM;
    const short* vp = vC + ((size_t)b * CCH + hh * HDIM) * NK;

    // init V pad rows 48..63 of every key-chunk: row 48 = 1.0 (l-column), rest 0
    {
        int bufi = t >> 7, rem = t & 127;          // 128 slots = 8 chunks x 16 rows
        int ch = rem >> 4, row = 48 + (rem & 15);
        b16x8 val = {};
        if (row == 48)
            #pragma unroll
            for (int e = 0; e < 8; e++) val[e] = (short)0x3F80;
        *(b16x8*)(&Vl[bufi][(ch * 64 + row) * 8]) = val;
    }

    // Q B-frags (persist): lane holds q = c (per qb), d = dc*16 + h*8 + e
    b16x8 qf[2][3];
    #pragma unroll
    for (int qb = 0; qb < 2; qb++)
        #pragma unroll
        for (int dc = 0; dc < 3; dc++)
            qf[qb][dc] = *(const b16x8*)(qp + (size_t)(n0 + qb * 32 + c) * CCH + dc * 16 + h * 8);

    // hoisted staging geometry (tile-invariant):  taskA = t, taskB = t + 256
    const int rowS = t & 63;                       // == taskB & 63
    const int chA = t >> 6;                        // 0..3
    const int keyS = (rowS & 51) | ((rowS & 4) << 1) | ((rowS & 8) >> 1);
    const short* ksrcA = kp + (size_t)keyS * CCH + chA * 8;  // always valid (chA<6)
    const bool  kvalB = (chA + 4) < 6;
    const bool  vval  = rowS < 48;
    const short* vsrcA = vp + (size_t)rowS * NK + chA * 8;
    const int taskA8 = t * 8, taskB8 = (t + 256) * 8;

    auto stage = [&](int m0, int bi) {
        size_t koff = (size_t)m0 * CCH;
        g2lds16(ksrcA + koff, &Kl[bi][taskA8]);
        if (kvalB) g2lds16(ksrcA + koff + 32, &Kl[bi][taskB8]);
        if (vval) {
            g2lds16(vsrcA + m0, &Vl[bi][taskA8]);
            g2lds16(vsrcA + m0 + 32, &Vl[bi][taskB8]);
        }
    };

    f32x16 O[2][2] = {};       // [qb][dblock];  O[qb][1] col c=16 accumulates l

    stage(0, 0);
    for (int tt = 0; tt < 16; ++tt) {
        __syncthreads();       // drains global_load_lds + joins waves
        if (tt < 15) stage((tt + 1) * 64, (tt + 1) & 1);
        const short* Kb = Kl[tt & 1];
        const short* Vb = Vl[tt & 1];
        #pragma unroll
        for (int kb = 0; kb < 2; kb++) {
            b16x8 kf[3];
            #pragma unroll
            for (int dc = 0; dc < 3; dc++)
                kf[dc] = *(const b16x8*)(Kb + (((dc * 2 + h) * 64) + kb * 32 + c) * 8);
            f32x16 s0v = {}, s1v = {};
            __builtin_amdgcn_s_setprio(1);
            #pragma unroll
            for (int dc = 0; dc < 3; dc++) {
                s0v = __builtin_amdgcn_mfma_f32_32x32x16_bf16(kf[dc], qf[0][dc], s0v, 0, 0, 0);
                s1v = __builtin_amdgcn_mfma_f32_32x32x16_bf16(kf[dc], qf[1][dc], s1v, 0, 0, 0);
            }
            __builtin_amdgcn_s_setprio(0);
            b16x8 pfrag[2][2];
            #pragma unroll
            for (int qb = 0; qb < 2; qb++) {
                float p[16];
                #pragma unroll
                for (int r = 0; r < 16; r++)
                    p[r] = __builtin_amdgcn_exp2f(qb ? s1v[r] : s0v[r]);
                #pragma unroll
                for (int kk = 0; kk < 2; kk++) {
                    union { unsigned u[4]; b16x8 v; } w;
                    #pragma unroll
                    for (int wd = 0; wd < 4; wd++)
                        asm("v_cvt_pk_bf16_f32 %0, %1, %2"
                            : "=v"(w.u[wd])
                            : "v"(p[kk * 8 + wd * 2]), "v"(p[kk * 8 + wd * 2 + 1]));
                    pfrag[qb][kk] = w.v;
                }
            }
            __builtin_amdgcn_s_setprio(1);
            #pragma unroll
            for (int kk = 0; kk < 2; kk++)
                #pragma unroll
                for (int db = 0; db < 2; db++) {
                    b16x8 vf = *(const b16x8*)(Vb + (((kb * 4 + kk * 2 + h) * 64) + db * 32 + c) * 8);
                    #pragma unroll
                    for (int qb = 0; qb < 2; qb++)
                        O[qb][db] = __builtin_amdgcn_mfma_f32_32x32x16_bf16(pfrag[qb][kk], vf, O[qb][db], 0, 0, 0);
                }
            __builtin_amdgcn_s_setprio(0);
        }
    }

    __syncthreads();   // all waves done reading V before Olw overlays it
    // l[q-slot r] lives in lane (h, c=16) at O[qb][1][r]; wave-private bounce
    short* Olw = ((short*)Vl) + wave * 2048;   // 4 KB per wave
    #pragma unroll
    for (int qb = 0; qb < 2; qb++) {
        #pragma unroll
        for (int r = 0; r < 16; r++) {
            int qrow = (r & 3) + 8 * (r >> 2) + 4 * h;
            float lr = __shfl(O[qb][1][r], (lane & 32) | 16);
            float iq = 1.0f / lr;
            #pragma unroll
            for (int db = 0; db < 2; db++) {
                int d = db * 32 + c;
                if (d < 48)
                    Olw[qrow * 64 + (((d >> 3) ^ (qrow & 7)) * 8) + (d & 7)] =
                        (short)f2bf(O[qb][db][r] * iq);
            }
        }
        // DS ops are in-order per wave; Olw is wave-private -> no barrier
        #pragma unroll
        for (int it = 0; it < 4; it++) {
            int idx = it * 64 + lane;
            int row = idx >> 3, c8 = idx & 7;
            if (c8 < 6) {
                b16x8 val = *(const b16x8*)(Olw + row * 64 + ((c8 ^ (row & 7)) * 8));
                *(b16x8*)(attT + ((size_t)b * NQ + n0 + qb * 32 + row) * CCH + hh * HDIM + c8 * 8) = val;
            }
        }
    }
}

// ---------------------------------------------------------------------------
extern "C" void kernel_launch(void* const* d_in, const int* in_sizes, int n_in,
                              void* d_out, int out_size, void* d_ws, size_t ws_size,
                              hipStream_t stream) {
    const float* x    = (const float*)d_in[0];
    const float* Wq   = (const float*)d_in[1];
    const float* Wk   = (const float*)d_in[2];
    const float* Wv   = (const float*)d_in[3];
    const float* Wsr  = (const float*)d_in[4];
    const float* bsr  = (const float*)d_in[5];
    const float* Wp   = (const float*)d_in[6];
    const float* bp   = (const float*)d_in[7];
    const float* relh = (const float*)d_in[8];
    const float* relw = (const float*)d_in[9];
    float* out = (float*)d_out;

    short* ws = (short*)d_ws;
    size_t off = 0;
    auto alloc = [&](size_t n) { short* p = ws + off; off += n; return p; };
    short* WqB  = alloc(147456);
    short* WkvB = alloc(294912);
    short* WsrT = alloc(589824);
    short* WpB  = alloc(147456);
    short* WcB  = alloc(768 * 1536);
    short* kvbh = alloc(768 * 2);         // fp32 kvbias (768 floats)
    short* xT   = alloc((size_t)BATCH * NQ * CCH);
    short* qTb  = alloc((size_t)BATCH * NQ * CCH);
    short* kTb  = alloc((size_t)BATCH * NK * CCH);
    short* vCb  = alloc((size_t)BATCH * CCH * NK);
    short* attT = alloc((size_t)BATCH * NQ * CCH);
    float* kvb  = (float*)kvbh;

    // weights cvt + kvbias + x transpose, one dispatch
    prep_kern<<<dim3(576, 7), 256, 0, stream>>>(Wq, Wk, Wv, Wsr, Wp, bsr, x,
                                                WqB, WkvB, WsrT, WpB, kvb, xT);
    // Wc = Wkv @ Wsr  (combined conv+projection weights)
    combine_gemm<<<dim3(6, 12), 256, 0, stream>>>(WsrT, WkvB, WcB);
    // fused Q -> qT  AND  KV direct from x (im2col, +kvbias, k: +pos *scale)
    fused_qkv<<<dim3(144, 1, BATCH), 256, 0, stream>>>(
        WqB, WcB, xT, kvb, relh, relw, qTb, kTb, vCb);
    // attention (512 blocks, XCD-swizzled, LDS-staged K/V, QBLK64)
    attn_kern<<<dim3(512), 256, 0, stream>>>(qTb, kTb, vCb, attT);
    // output projection (+bp), f32 natural layout
    p_gemm<<<dim3(32, 3, BATCH), 256, 0, stream>>>(WpB, attT, out, bp);
}

// Round 14
// 111.876 us; speedup vs baseline: 1.7191x; 1.0957x over previous
//
#include <hip/hip_runtime.h>
#include <hip/hip_bf16.h>
#include <math.h>

typedef __attribute__((ext_vector_type(8))) short b16x8;
typedef __attribute__((ext_vector_type(4))) short b16x4;
typedef __attribute__((ext_vector_type(4))) float floatx4;
typedef __attribute__((ext_vector_type(16))) float f32x16;

constexpr int BATCH = 4, CCH = 384, NQ = 4096, NHD = 8, HDIM = 48, NK = 1024;
constexpr float SCALE_L2E = 0.14433756729740643f * 1.4426950408889634f; // 48^-0.5 * log2(e)

__device__ inline unsigned short f2bf(float f) {
    unsigned u = __builtin_bit_cast(unsigned, f);
    u += 0x7fffu + ((u >> 16) & 1u);
    return (unsigned short)(u >> 16);
}

__device__ __forceinline__ void g2lds16(const void* g, void* l) {
    __builtin_amdgcn_global_load_lds(
        (const __attribute__((address_space(1))) unsigned int*)g,
        (__attribute__((address_space(3))) unsigned int*)l, 16, 0, 0);
}

// ---------------------------------------------------------------------------
// PREP (one dispatch): weight cvt fp32->bf16 + x transpose.
// job 0: Wq; 1: Wk -> WkvB; 2: Wv -> WkvB+147456; 3: Wsr reorder to
// [o][pos*384+c] (pos=i*2+j); 4: Wp; 5: x -> xT[b][s][c] bf16.
// ---------------------------------------------------------------------------
__global__ void prep_kern(const float* __restrict__ Wq, const float* __restrict__ Wk,
                          const float* __restrict__ Wv, const float* __restrict__ Wsr,
                          const float* __restrict__ Wp, const float* __restrict__ x,
                          short* __restrict__ WqB, short* __restrict__ WkvB,
                          short* __restrict__ WsrB, short* __restrict__ WpB,
                          short* __restrict__ xT) {
    int job = blockIdx.y;
    if (job == 5) {   // x [B][384][4096] f32 -> xT [B][4096][384] bf16
        for (int i = blockIdx.x * 256 + threadIdx.x; i < BATCH * 4096 * 48;
             i += 576 * 256) {
            int b = i / (4096 * 48);
            int rem = i - b * (4096 * 48);
            int c8 = rem / 4096, s = rem - c8 * 4096;
            b16x8 pk;
            #pragma unroll
            for (int e = 0; e < 8; e++)
                pk[e] = (short)f2bf(x[((size_t)b * CCH + c8 * 8 + e) * NQ + s]);
            *(b16x8*)(xT + ((size_t)b * NQ + s) * CCH + c8 * 8) = pk;
        }
        return;
    }
    if (job == 3) {   // WsrB[o][ (r&3)*384 + (r>>2) ] = Wsr[o][r],  r = c*4+p
        for (int i = blockIdx.x * 256 + threadIdx.x; i < 589824; i += gridDim.x * 256) {
            int o = i / 1536, r = i - o * 1536;
            WsrB[o * 1536 + (r & 3) * 384 + (r >> 2)] = (short)f2bf(Wsr[i]);
        }
        return;
    }
    const float* src; short* dst;
    if (job == 0)      { src = Wq;  dst = WqB; }
    else if (job == 1) { src = Wk;  dst = WkvB; }
    else if (job == 2) { src = Wv;  dst = WkvB + 147456; }
    else               { src = Wp;  dst = WpB; }
    for (int i = blockIdx.x * 256 + threadIdx.x; i < 147456; i += gridDim.x * 256)
        dst[i] = (short)f2bf(src[i]);
}

// ---------------------------------------------------------------------------
// FUSED conv+Q GEMM (480 blocks).  id<24 per batch: SR-conv as GEMM (im2col
// from xT, K=1536, +bsr) -> xsrT[ssr][c].  Else: Q (K=384) -> qT[n][c].
// 128x128 tile, BK=64, global_load_lds staging (linear dest, inverse-XOR
// swizzled source), 4 waves x 4x4 frags of 16x16x32.
// ---------------------------------------------------------------------------
__global__ __launch_bounds__(256, 2) void fused_gemm1(
    const short* __restrict__ WsrB, const short* __restrict__ WqB,
    const short* __restrict__ xT, const float* __restrict__ bsr,
    short* __restrict__ xsrT, short* __restrict__ qTb)
{
    __shared__ short At[128 * 64];
    __shared__ short Bt[128 * 64];
    const int b = blockIdx.z;
    const int id = blockIdx.x;
    const bool conv = id < 24;
    const int sx = conv ? (id & 7) : ((id - 24) & 31);
    const int oy = conv ? (id >> 3) : ((id - 24) >> 5);
    const int Ks = conv ? 1536 : 384;
    const int S  = conv ? NK : NQ;
    const short* A = conv ? WsrB : WqB;
    short* Yt = conv ? xsrT : qTb;
    const int o0 = oy * 128, s0 = sx * 128;
    const int t = threadIdx.x, wave = t >> 6, lane = t & 63, g = lane >> 4, li = lane & 15;
    const int wr = wave >> 1, wc = wave & 1;
    floatx4 acc[4][4] = {};
    const short* Bbase = xT + (size_t)b * NQ * CCH;

    for (int k0 = 0; k0 < Ks; k0 += 64) {
        __syncthreads();
        #pragma unroll
        for (int it = 0; it < 4; it++) {
            int task = it * 256 + t;
            int row = task >> 3, ch = task & 7;
            int cont = ch ^ (row & 7);
            g2lds16(A + (size_t)(o0 + row) * Ks + k0 + cont * 8, At + task * 8);
        }
        #pragma unroll
        for (int it = 0; it < 4; it++) {
            int task = it * 256 + t;
            int row = task >> 3, ch = task & 7;
            int cont = ch ^ (row & 7);
            if (conv) {
                int ssr = s0 + row;
                int hs = ssr >> 5, wsv = ssr & 31;
                int k = k0 + cont * 8;
                int p = k / 384, coff = k - p * 384;
                g2lds16(Bbase + (size_t)((2 * hs + (p >> 1)) * 64 + 2 * wsv + (p & 1)) * 384 + coff,
                        Bt + task * 8);
            } else {
                g2lds16(Bbase + (size_t)(s0 + row) * 384 + k0 + cont * 8, Bt + task * 8);
            }
        }
        __syncthreads();
        #pragma unroll
        for (int kk = 0; kk < 2; kk++) {
            b16x8 af[4], bf[4];
            #pragma unroll
            for (int mi = 0; mi < 4; mi++) {
                int r = wr * 64 + mi * 16 + li;
                af[mi] = *(const b16x8*)(At + r * 64 + (((kk * 4 + g) ^ (r & 7)) * 8));
            }
            #pragma unroll
            for (int nf = 0; nf < 4; nf++) {
                int r = wc * 64 + nf * 16 + li;
                bf[nf] = *(const b16x8*)(Bt + r * 64 + (((kk * 4 + g) ^ (r & 7)) * 8));
            }
            #pragma unroll
            for (int mi = 0; mi < 4; mi++)
                #pragma unroll
                for (int nf = 0; nf < 4; nf++)
                    acc[mi][nf] = __builtin_amdgcn_mfma_f32_16x16x32_bf16(af[mi], bf[nf], acc[mi][nf], 0, 0, 0);
        }
    }

    #pragma unroll
    for (int mi = 0; mi < 4; mi++) {
        #pragma unroll
        for (int nf = 0; nf < 4; nf++) {
            int o = o0 + wr * 64 + mi * 16 + g * 4;
            int s = s0 + wc * 64 + nf * 16 + li;
            b16x4 pk;
            #pragma unroll
            for (int j = 0; j < 4; j++) {
                float v = acc[mi][nf][j];
                if (conv) v += bsr[o + j];
                pk[j] = (short)f2bf(v);
            }
            *(b16x4*)(Yt + ((size_t)b * S + s) * CCH + o) = pk;
        }
    }
}

// ---------------------------------------------------------------------------
// KV GEMM (K=384, from xsrT): o<384 -> k (+pos, *SCALE_L2E) -> kT[m][c];
// o>=384 -> v -> vC[c][m] channel-major.
// ---------------------------------------------------------------------------
__global__ __launch_bounds__(256, 2) void kv_gemm(
    const short* __restrict__ WkvB, const short* __restrict__ xsrT,
    const float* __restrict__ relh, const float* __restrict__ relw,
    short* __restrict__ kTb, short* __restrict__ vCb)
{
    __shared__ short At[128 * 64];
    __shared__ short Bt[128 * 64];
    const int b = blockIdx.z, o0 = blockIdx.y * 128, s0 = blockIdx.x * 128;
    const int t = threadIdx.x, wave = t >> 6, lane = t & 63, g = lane >> 4, li = lane & 15;
    const int wr = wave >> 1, wc = wave & 1;
    floatx4 acc[4][4] = {};
    const short* Bbase = xsrT + (size_t)b * NK * CCH;

    for (int k0 = 0; k0 < 384; k0 += 64) {
        __syncthreads();
        #pragma unroll
        for (int it = 0; it < 4; it++) {
            int task = it * 256 + t;
            int row = task >> 3, ch = task & 7;
            int cont = ch ^ (row & 7);
            g2lds16(WkvB + (size_t)(o0 + row) * 384 + k0 + cont * 8, At + task * 8);
        }
        #pragma unroll
        for (int it = 0; it < 4; it++) {
            int task = it * 256 + t;
            int row = task >> 3, ch = task & 7;
            int cont = ch ^ (row & 7);
            g2lds16(Bbase + (size_t)(s0 + row) * 384 + k0 + cont * 8, Bt + task * 8);
        }
        __syncthreads();
        #pragma unroll
        for (int kk = 0; kk < 2; kk++) {
            b16x8 af[4], bf[4];
            #pragma unroll
            for (int mi = 0; mi < 4; mi++) {
                int r = wr * 64 + mi * 16 + li;
                af[mi] = *(const b16x8*)(At + r * 64 + (((kk * 4 + g) ^ (r & 7)) * 8));
            }
            #pragma unroll
            for (int nf = 0; nf < 4; nf++) {
                int r = wc * 64 + nf * 16 + li;
                bf[nf] = *(const b16x8*)(Bt + r * 64 + (((kk * 4 + g) ^ (r & 7)) * 8));
            }
            #pragma unroll
            for (int mi = 0; mi < 4; mi++)
                #pragma unroll
                for (int nf = 0; nf < 4; nf++)
                    acc[mi][nf] = __builtin_amdgcn_mfma_f32_16x16x32_bf16(af[mi], bf[nf], acc[mi][nf], 0, 0, 0);
        }
    }

    #pragma unroll
    for (int mi = 0; mi < 4; mi++) {
        #pragma unroll
        for (int nf = 0; nf < 4; nf++) {
            int o = o0 + wr * 64 + mi * 16 + g * 4;
            int s = s0 + wc * 64 + nf * 16 + li;
            if (o0 < 384) {
                // pos[m] = rel_h[o][m & 31] + rel_w[o][m >> 5]
                int hs = s >> 5, wsv = s & 31;
                b16x4 pk;
                #pragma unroll
                for (int j = 0; j < 4; j++)
                    pk[j] = (short)f2bf((acc[mi][nf][j] + relh[(o + j) * 32 + wsv]
                                         + relw[(o + j) * 32 + hs]) * SCALE_L2E);
                *(b16x4*)(kTb + ((size_t)b * NK + s) * CCH + o) = pk;
            } else {
                #pragma unroll
                for (int j = 0; j < 4; j++)
                    vCb[((size_t)b * CCH + (o - 384 + j)) * NK + s] = (short)f2bf(acc[mi][nf][j]);
            }
        }
    }
}

// ---------------------------------------------------------------------------
// P projection GEMM: out[o][s] f32 = sum_k Wp[o][k] * attT[s][k] + bp[o].
// ---------------------------------------------------------------------------
__global__ __launch_bounds__(256, 2) void p_gemm(
    const short* __restrict__ A, const short* __restrict__ Bm,
    float* __restrict__ Yf, const float* __restrict__ bias)
{
    __shared__ short At[128 * 64];
    __shared__ short Bt[128 * 64];
    const int b = blockIdx.z, o0 = blockIdx.y * 128, s0 = blockIdx.x * 128;
    const int t = threadIdx.x, wave = t >> 6, lane = t & 63, g = lane >> 4, li = lane & 15;
    const int wr = wave >> 1, wc = wave & 1;
    floatx4 acc[4][4] = {};
    const short* Bbase = Bm + (size_t)b * NQ * CCH;

    for (int k0 = 0; k0 < 384; k0 += 64) {
        __syncthreads();
        #pragma unroll
        for (int it = 0; it < 4; it++) {
            int task = it * 256 + t;
            int row = task >> 3, ch = task & 7;
            int cont = ch ^ (row & 7);
            g2lds16(A + (size_t)(o0 + row) * 384 + k0 + cont * 8, At + task * 8);
        }
        #pragma unroll
        for (int it = 0; it < 4; it++) {
            int task = it * 256 + t;
            int row = task >> 3, ch = task & 7;
            int cont = ch ^ (row & 7);
            g2lds16(Bbase + (size_t)(s0 + row) * 384 + k0 + cont * 8, Bt + task * 8);
        }
        __syncthreads();
        #pragma unroll
        for (int kk = 0; kk < 2; kk++) {
            b16x8 af[4], bf[4];
            #pragma unroll
            for (int mi = 0; mi < 4; mi++) {
                int r = wr * 64 + mi * 16 + li;
                af[mi] = *(const b16x8*)(At + r * 64 + (((kk * 4 + g) ^ (r & 7)) * 8));
            }
            #pragma unroll
            for (int nf = 0; nf < 4; nf++) {
                int r = wc * 64 + nf * 16 + li;
                bf[nf] = *(const b16x8*)(Bt + r * 64 + (((kk * 4 + g) ^ (r & 7)) * 8));
            }
            #pragma unroll
            for (int mi = 0; mi < 4; mi++)
                #pragma unroll
                for (int nf = 0; nf < 4; nf++)
                    acc[mi][nf] = __builtin_amdgcn_mfma_f32_16x16x32_bf16(af[mi], bf[nf], acc[mi][nf], 0, 0, 0);
        }
    }

    #pragma unroll
    for (int mi = 0; mi < 4; mi++) {
        #pragma unroll
        for (int nf = 0; nf < 4; nf++) {
            int o = o0 + wr * 64 + mi * 16 + g * 4;
            int s = s0 + wc * 64 + nf * 16 + li;
            #pragma unroll
            for (int j = 0; j < 4; j++)
                Yf[((size_t)b * CCH + o + j) * (size_t)NQ + s] = acc[mi][nf][j] + bias[o + j];
        }
    }
}

// ---------------------------------------------------------------------------
// Flash attention v8 (round-13 verified): QBLK 64/wave, 256 q/block, 512
// blocks.  LDS-staged K/V (chunk-major, conflict-free), K rows bit-2/3-swap
// permuted -> zero cross-lane exchange; l via ones-row MFMA; exp2 builtin;
// cvt_pk pack; hoisted staging addresses.
// ---------------------------------------------------------------------------
__global__ __launch_bounds__(256, 2) void attn_kern(
    const short* __restrict__ qT, const short* __restrict__ kT,
    const short* __restrict__ vC, short* __restrict__ attT)
{
    __shared__ short Kl[2][6 * 64 * 8];   // [buf][d-chunk 0..5][row][8]
    __shared__ short Vl[2][8 * 64 * 8];   // [buf][key-chunk 0..7][d-row][8]
    const int wgid = blockIdx.x;
    const int nid = (wgid & 7) * 64 + (wgid >> 3);     // XCD swizzle (512 = 8*64)
    const int qt = nid & 15, hh = (nid >> 4) & 7, b = nid >> 7;
    const int t = threadIdx.x, wave = t >> 6, lane = t & 63;
    const int h = lane >> 5, c = lane & 31;
    const int n0 = qt * 256 + wave * 64;

    const short* qp = qT + (size_t)b * NQ * CCH + hh * HDIM;
    const short* kp = kT + (size_t)b * NK * CCH + hh * HDIM;
    const short* vp = vC + ((size_t)b * CCH + hh * HDIM) * NK;

    // init V pad rows 48..63 of every key-chunk: row 48 = 1.0 (l-column), rest 0
    {
        int bufi = t >> 7, rem = t & 127;          // 128 slots = 8 chunks x 16 rows
        int ch = rem >> 4, row = 48 + (rem & 15);
        b16x8 val = {};
        if (row == 48)
            #pragma unroll
            for (int e = 0; e < 8; e++) val[e] = (short)0x3F80;
        *(b16x8*)(&Vl[bufi][(ch * 64 + row) * 8]) = val;
    }

    // Q B-frags (persist): lane holds q = c (per qb), d = dc*16 + h*8 + e
    b16x8 qf[2][3];
    #pragma unroll
    for (int qb = 0; qb < 2; qb++)
        #pragma unroll
        for (int dc = 0; dc < 3; dc++)
            qf[qb][dc] = *(const b16x8*)(qp + (size_t)(n0 + qb * 32 + c) * CCH + dc * 16 + h * 8);

    // hoisted staging geometry (tile-invariant):  taskA = t, taskB = t + 256
    const int rowS = t & 63;
    const int chA = t >> 6;                        // 0..3
    const int keyS = (rowS & 51) | ((rowS & 4) << 1) | ((rowS & 8) >> 1);
    const short* ksrcA = kp + (size_t)keyS * CCH + chA * 8;
    const bool  kvalB = (chA + 4) < 6;
    const bool  vval  = rowS < 48;
    const short* vsrcA = vp + (size_t)rowS * NK + chA * 8;
    const int taskA8 = t * 8, taskB8 = (t + 256) * 8;

    auto stage = [&](int m0, int bi) {
        size_t koff = (size_t)m0 * CCH;
        g2lds16(ksrcA + koff, &Kl[bi][taskA8]);
        if (kvalB) g2lds16(ksrcA + koff + 32, &Kl[bi][taskB8]);
        if (vval) {
            g2lds16(vsrcA + m0, &Vl[bi][taskA8]);
            g2lds16(vsrcA + m0 + 32, &Vl[bi][taskB8]);
        }
    };

    f32x16 O[2][2] = {};       // [qb][dblock];  O[qb][1] col c=16 accumulates l

    stage(0, 0);
    for (int tt = 0; tt < 16; ++tt) {
        __syncthreads();       // drains global_load_lds + joins waves
        if (tt < 15) stage((tt + 1) * 64, (tt + 1) & 1);
        const short* Kb = Kl[tt & 1];
        const short* Vb = Vl[tt & 1];
        #pragma unroll
        for (int kb = 0; kb < 2; kb++) {
            b16x8 kf[3];
            #pragma unroll
            for (int dc = 0; dc < 3; dc++)
                kf[dc] = *(const b16x8*)(Kb + (((dc * 2 + h) * 64) + kb * 32 + c) * 8);
            f32x16 s0v = {}, s1v = {};
            __builtin_amdgcn_s_setprio(1);
            #pragma unroll
            for (int dc = 0; dc < 3; dc++) {
                s0v = __builtin_amdgcn_mfma_f32_32x32x16_bf16(kf[dc], qf[0][dc], s0v, 0, 0, 0);
                s1v = __builtin_amdgcn_mfma_f32_32x32x16_bf16(kf[dc], qf[1][dc], s1v, 0, 0, 0);
            }
            __builtin_amdgcn_s_setprio(0);
            b16x8 pfrag[2][2];
            #pragma unroll
            for (int qb = 0; qb < 2; qb++) {
                float p[16];
                #pragma unroll
                for (int r = 0; r < 16; r++)
                    p[r] = __builtin_amdgcn_exp2f(qb ? s1v[r] : s0v[r]);
                #pragma unroll
                for (int kk = 0; kk < 2; kk++) {
                    union { unsigned u[4]; b16x8 v; } w;
                    #pragma unroll
                    for (int wd = 0; wd < 4; wd++)
                        asm("v_cvt_pk_bf16_f32 %0, %1, %2"
                            : "=v"(w.u[wd])
                            : "v"(p[kk * 8 + wd * 2]), "v"(p[kk * 8 + wd * 2 + 1]));
                    pfrag[qb][kk] = w.v;
                }
            }
            __builtin_amdgcn_s_setprio(1);
            #pragma unroll
            for (int kk = 0; kk < 2; kk++)
                #pragma unroll
                for (int db = 0; db < 2; db++) {
                    b16x8 vf = *(const b16x8*)(Vb + (((kb * 4 + kk * 2 + h) * 64) + db * 32 + c) * 8);
                    #pragma unroll
                    for (int qb = 0; qb < 2; qb++)
                        O[qb][db] = __builtin_amdgcn_mfma_f32_32x32x16_bf16(pfrag[qb][kk], vf, O[qb][db], 0, 0, 0);
                }
            __builtin_amdgcn_s_setprio(0);
        }
    }

    __syncthreads();   // all waves done reading V before Olw overlays it
    // l[q-slot r] lives in lane (h, c=16) at O[qb][1][r]; wave-private bounce
    short* Olw = ((short*)Vl) + wave * 2048;   // 4 KB per wave
    #pragma unroll
    for (int qb = 0; qb < 2; qb++) {
        #pragma unroll
        for (int r = 0; r < 16; r++) {
            int qrow = (r & 3) + 8 * (r >> 2) + 4 * h;
            float lr = __shfl(O[qb][1][r], (lane & 32) | 16);
            float iq = 1.0f / lr;
            #pragma unroll
            for (int db = 0; db < 2; db++) {
                int d = db * 32 + c;
                if (d < 48)
                    Olw[qrow * 64 + (((d >> 3) ^ (qrow & 7)) * 8) + (d & 7)] =
                        (short)f2bf(O[qb][db][r] * iq);
            }
        }
        // DS ops are in-order per wave; Olw is wave-private -> no barrier
        #pragma unroll
        for (int it = 0; it < 4; it++) {
            int idx = it * 64 + lane;
            int row = idx >> 3, c8 = idx & 7;
            if (c8 < 6) {
                b16x8 val = *(const b16x8*)(Olw + row * 64 + ((c8 ^ (row & 7)) * 8));
                *(b16x8*)(attT + ((size_t)b * NQ + n0 + qb * 32 + row) * CCH + hh * HDIM + c8 * 8) = val;
            }
        }
    }
}

// ---------------------------------------------------------------------------
extern "C" void kernel_launch(void* const* d_in, const int* in_sizes, int n_in,
                              void* d_out, int out_size, void* d_ws, size_t ws_size,
                              hipStream_t stream) {
    const float* x    = (const float*)d_in[0];
    const float* Wq   = (const float*)d_in[1];
    const float* Wk   = (const float*)d_in[2];
    const float* Wv   = (const float*)d_in[3];
    const float* Wsr  = (const float*)d_in[4];
    const float* bsr  = (const float*)d_in[5];
    const float* Wp   = (const float*)d_in[6];
    const float* bp   = (const float*)d_in[7];
    const float* relh = (const float*)d_in[8];
    const float* relw = (const float*)d_in[9];
    float* out = (float*)d_out;

    short* ws = (short*)d_ws;
    size_t off = 0;
    auto alloc = [&](size_t n) { short* p = ws + off; off += n; return p; };
    short* WqB  = alloc(147456);
    short* WkvB = alloc(294912);
    short* WsrB = alloc(589824);
    short* WpB  = alloc(147456);
    short* xT   = alloc((size_t)BATCH * NQ * CCH);
    short* xsrT = alloc((size_t)BATCH * NK * CCH);
    short* qTb  = alloc((size_t)BATCH * NQ * CCH);
    short* kTb  = alloc((size_t)BATCH * NK * CCH);
    short* vCb  = alloc((size_t)BATCH * CCH * NK);
    short* attT = alloc((size_t)BATCH * NQ * CCH);

    // weights cvt + x transpose, one dispatch
    prep_kern<<<dim3(576, 6), 256, 0, stream>>>(Wq, Wk, Wv, Wsr, Wp, x,
                                                WqB, WkvB, WsrB, WpB, xT);
    // fused SR-conv (+bsr) -> xsrT  AND  Q projection -> qT
    fused_gemm1<<<dim3(120, 1, BATCH), 256, 0, stream>>>(WsrB, WqB, xT, bsr, xsrT, qTb);
    // KV from xsrT: k (+pos, *SCALE_L2E) -> kT, v -> vC
    kv_gemm<<<dim3(8, 6, BATCH), 256, 0, stream>>>(WkvB, xsrT, relh, relw, kTb, vCb);
    // attention (512 blocks, XCD-swizzled, LDS-staged K/V, QBLK64)
    attn_kern<<<dim3(512), 256, 0, stream>>>(qTb, kTb, vCb, attT);
    // output projection (+bp), f32 natural layout
    p_gemm<<<dim3(32, 3, BATCH), 256, 0, stream>>>(WpB, attT, out, bp);
}

// Round 15
// 111.354 us; speedup vs baseline: 1.7272x; 1.0047x over previous
//
#include <hip/hip_runtime.h>
#include <hip/hip_bf16.h>
#include <math.h>

typedef __attribute__((ext_vector_type(8))) short b16x8;
typedef __attribute__((ext_vector_type(4))) short b16x4;
typedef __attribute__((ext_vector_type(4))) float floatx4;
typedef __attribute__((ext_vector_type(16))) float f32x16;

constexpr int BATCH = 4, CCH = 384, NQ = 4096, NHD = 8, HDIM = 48, NK = 1024;
constexpr float SCALE_L2E = 0.14433756729740643f * 1.4426950408889634f; // 48^-0.5 * log2(e)

__device__ inline unsigned short f2bf(float f) {
    unsigned u = __builtin_bit_cast(unsigned, f);
    u += 0x7fffu + ((u >> 16) & 1u);
    return (unsigned short)(u >> 16);
}

__device__ __forceinline__ void g2lds16(const void* g, void* l) {
    __builtin_amdgcn_global_load_lds(
        (const __attribute__((address_space(1))) unsigned int*)g,
        (__attribute__((address_space(3))) unsigned int*)l, 16, 0, 0);
}

// ---------------------------------------------------------------------------
// PREP (one dispatch): weight cvt fp32->bf16 + x transpose.
// ---------------------------------------------------------------------------
__global__ void prep_kern(const float* __restrict__ Wq, const float* __restrict__ Wk,
                          const float* __restrict__ Wv, const float* __restrict__ Wsr,
                          const float* __restrict__ Wp, const float* __restrict__ x,
                          short* __restrict__ WqB, short* __restrict__ WkvB,
                          short* __restrict__ WsrB, short* __restrict__ WpB,
                          short* __restrict__ xT) {
    int job = blockIdx.y;
    if (job == 5) {   // x [B][384][4096] f32 -> xT [B][4096][384] bf16
        for (int i = blockIdx.x * 256 + threadIdx.x; i < BATCH * 4096 * 48;
             i += 576 * 256) {
            int b = i / (4096 * 48);
            int rem = i - b * (4096 * 48);
            int c8 = rem / 4096, s = rem - c8 * 4096;
            b16x8 pk;
            #pragma unroll
            for (int e = 0; e < 8; e++)
                pk[e] = (short)f2bf(x[((size_t)b * CCH + c8 * 8 + e) * NQ + s]);
            *(b16x8*)(xT + ((size_t)b * NQ + s) * CCH + c8 * 8) = pk;
        }
        return;
    }
    if (job == 3) {   // WsrB[o][ (r&3)*384 + (r>>2) ] = Wsr[o][r],  r = c*4+p
        for (int i = blockIdx.x * 256 + threadIdx.x; i < 589824; i += gridDim.x * 256) {
            int o = i / 1536, r = i - o * 1536;
            WsrB[o * 1536 + (r & 3) * 384 + (r >> 2)] = (short)f2bf(Wsr[i]);
        }
        return;
    }
    const float* src; short* dst;
    if (job == 0)      { src = Wq;  dst = WqB; }
    else if (job == 1) { src = Wk;  dst = WkvB; }
    else if (job == 2) { src = Wv;  dst = WkvB + 147456; }
    else               { src = Wp;  dst = WpB; }
    for (int i = blockIdx.x * 256 + threadIdx.x; i < 147456; i += gridDim.x * 256)
        dst[i] = (short)f2bf(src[i]);
}

// ---------------------------------------------------------------------------
// FUSED conv+Q GEMM (480 blocks).  id<24 per batch: SR-conv (im2col, K=1536,
// +bsr) -> xsrT.  Else: Q (K=384) -> qT.
// ---------------------------------------------------------------------------
__global__ __launch_bounds__(256, 2) void fused_gemm1(
    const short* __restrict__ WsrB, const short* __restrict__ WqB,
    const short* __restrict__ xT, const float* __restrict__ bsr,
    short* __restrict__ xsrT, short* __restrict__ qTb)
{
    __shared__ short At[128 * 64];
    __shared__ short Bt[128 * 64];
    const int b = blockIdx.z;
    const int id = blockIdx.x;
    const bool conv = id < 24;
    const int sx = conv ? (id & 7) : ((id - 24) & 31);
    const int oy = conv ? (id >> 3) : ((id - 24) >> 5);
    const int Ks = conv ? 1536 : 384;
    const int S  = conv ? NK : NQ;
    const short* A = conv ? WsrB : WqB;
    short* Yt = conv ? xsrT : qTb;
    const int o0 = oy * 128, s0 = sx * 128;
    const int t = threadIdx.x, wave = t >> 6, lane = t & 63, g = lane >> 4, li = lane & 15;
    const int wr = wave >> 1, wc = wave & 1;
    floatx4 acc[4][4] = {};
    const short* Bbase = xT + (size_t)b * NQ * CCH;

    for (int k0 = 0; k0 < Ks; k0 += 64) {
        __syncthreads();
        #pragma unroll
        for (int it = 0; it < 4; it++) {
            int task = it * 256 + t;
            int row = task >> 3, ch = task & 7;
            int cont = ch ^ (row & 7);
            g2lds16(A + (size_t)(o0 + row) * Ks + k0 + cont * 8, At + task * 8);
        }
        #pragma unroll
        for (int it = 0; it < 4; it++) {
            int task = it * 256 + t;
            int row = task >> 3, ch = task & 7;
            int cont = ch ^ (row & 7);
            if (conv) {
                int ssr = s0 + row;
                int hs = ssr >> 5, wsv = ssr & 31;
                int k = k0 + cont * 8;
                int p = k / 384, coff = k - p * 384;
                g2lds16(Bbase + (size_t)((2 * hs + (p >> 1)) * 64 + 2 * wsv + (p & 1)) * 384 + coff,
                        Bt + task * 8);
            } else {
                g2lds16(Bbase + (size_t)(s0 + row) * 384 + k0 + cont * 8, Bt + task * 8);
            }
        }
        __syncthreads();
        #pragma unroll
        for (int kk = 0; kk < 2; kk++) {
            b16x8 af[4], bf[4];
            #pragma unroll
            for (int mi = 0; mi < 4; mi++) {
                int r = wr * 64 + mi * 16 + li;
                af[mi] = *(const b16x8*)(At + r * 64 + (((kk * 4 + g) ^ (r & 7)) * 8));
            }
            #pragma unroll
            for (int nf = 0; nf < 4; nf++) {
                int r = wc * 64 + nf * 16 + li;
                bf[nf] = *(const b16x8*)(Bt + r * 64 + (((kk * 4 + g) ^ (r & 7)) * 8));
            }
            #pragma unroll
            for (int mi = 0; mi < 4; mi++)
                #pragma unroll
                for (int nf = 0; nf < 4; nf++)
                    acc[mi][nf] = __builtin_amdgcn_mfma_f32_16x16x32_bf16(af[mi], bf[nf], acc[mi][nf], 0, 0, 0);
        }
    }

    #pragma unroll
    for (int mi = 0; mi < 4; mi++) {
        #pragma unroll
        for (int nf = 0; nf < 4; nf++) {
            int o = o0 + wr * 64 + mi * 16 + g * 4;
            int s = s0 + wc * 64 + nf * 16 + li;
            b16x4 pk;
            #pragma unroll
            for (int j = 0; j < 4; j++) {
                float v = acc[mi][nf][j];
                if (conv) v += bsr[o + j];
                pk[j] = (short)f2bf(v);
            }
            *(b16x4*)(Yt + ((size_t)b * S + s) * CCH + o) = pk;
        }
    }
}

// ---------------------------------------------------------------------------
// KV GEMM (K=384, from xsrT): o<384 -> k (+pos, *SCALE_L2E) -> kT[m][c];
// o>=384 -> v -> vC[c][m] channel-major.
// ---------------------------------------------------------------------------
__global__ __launch_bounds__(256, 2) void kv_gemm(
    const short* __restrict__ WkvB, const short* __restrict__ xsrT,
    const float* __restrict__ relh, const float* __restrict__ relw,
    short* __restrict__ kTb, short* __restrict__ vCb)
{
    __shared__ short At[128 * 64];
    __shared__ short Bt[128 * 64];
    const int b = blockIdx.z, o0 = blockIdx.y * 128, s0 = blockIdx.x * 128;
    const int t = threadIdx.x, wave = t >> 6, lane = t & 63, g = lane >> 4, li = lane & 15;
    const int wr = wave >> 1, wc = wave & 1;
    floatx4 acc[4][4] = {};
    const short* Bbase = xsrT + (size_t)b * NK * CCH;

    for (int k0 = 0; k0 < 384; k0 += 64) {
        __syncthreads();
        #pragma unroll
        for (int it = 0; it < 4; it++) {
            int task = it * 256 + t;
            int row = task >> 3, ch = task & 7;
            int cont = ch ^ (row & 7);
            g2lds16(WkvB + (size_t)(o0 + row) * 384 + k0 + cont * 8, At + task * 8);
        }
        #pragma unroll
        for (int it = 0; it < 4; it++) {
            int task = it * 256 + t;
            int row = task >> 3, ch = task & 7;
            int cont = ch ^ (row & 7);
            g2lds16(Bbase + (size_t)(s0 + row) * 384 + k0 + cont * 8, Bt + task * 8);
        }
        __syncthreads();
        #pragma unroll
        for (int kk = 0; kk < 2; kk++) {
            b16x8 af[4], bf[4];
            #pragma unroll
            for (int mi = 0; mi < 4; mi++) {
                int r = wr * 64 + mi * 16 + li;
                af[mi] = *(const b16x8*)(At + r * 64 + (((kk * 4 + g) ^ (r & 7)) * 8));
            }
            #pragma unroll
            for (int nf = 0; nf < 4; nf++) {
                int r = wc * 64 + nf * 16 + li;
                bf[nf] = *(const b16x8*)(Bt + r * 64 + (((kk * 4 + g) ^ (r & 7)) * 8));
            }
            #pragma unroll
            for (int mi = 0; mi < 4; mi++)
                #pragma unroll
                for (int nf = 0; nf < 4; nf++)
                    acc[mi][nf] = __builtin_amdgcn_mfma_f32_16x16x32_bf16(af[mi], bf[nf], acc[mi][nf], 0, 0, 0);
        }
    }

    #pragma unroll
    for (int mi = 0; mi < 4; mi++) {
        #pragma unroll
        for (int nf = 0; nf < 4; nf++) {
            int o = o0 + wr * 64 + mi * 16 + g * 4;
            int s = s0 + wc * 64 + nf * 16 + li;
            if (o0 < 384) {
                int hs = s >> 5, wsv = s & 31;
                b16x4 pk;
                #pragma unroll
                for (int j = 0; j < 4; j++)
                    pk[j] = (short)f2bf((acc[mi][nf][j] + relh[(o + j) * 32 + wsv]
                                         + relw[(o + j) * 32 + hs]) * SCALE_L2E);
                *(b16x4*)(kTb + ((size_t)b * NK + s) * CCH + o) = pk;
            } else {
                #pragma unroll
                for (int j = 0; j < 4; j++)
                    vCb[((size_t)b * CCH + (o - 384 + j)) * NK + s] = (short)f2bf(acc[mi][nf][j]);
            }
        }
    }
}

// ---------------------------------------------------------------------------
// P projection GEMM: out[o][s] f32 = sum_k Wp[o][k] * attT[s][k] + bp[o].
// ---------------------------------------------------------------------------
__global__ __launch_bounds__(256, 2) void p_gemm(
    const short* __restrict__ A, const short* __restrict__ Bm,
    float* __restrict__ Yf, const float* __restrict__ bias)
{
    __shared__ short At[128 * 64];
    __shared__ short Bt[128 * 64];
    const int b = blockIdx.z, o0 = blockIdx.y * 128, s0 = blockIdx.x * 128;
    const int t = threadIdx.x, wave = t >> 6, lane = t & 63, g = lane >> 4, li = lane & 15;
    const int wr = wave >> 1, wc = wave & 1;
    floatx4 acc[4][4] = {};
    const short* Bbase = Bm + (size_t)b * NQ * CCH;

    for (int k0 = 0; k0 < 384; k0 += 64) {
        __syncthreads();
        #pragma unroll
        for (int it = 0; it < 4; it++) {
            int task = it * 256 + t;
            int row = task >> 3, ch = task & 7;
            int cont = ch ^ (row & 7);
            g2lds16(A + (size_t)(o0 + row) * 384 + k0 + cont * 8, At + task * 8);
        }
        #pragma unroll
        for (int it = 0; it < 4; it++) {
            int task = it * 256 + t;
            int row = task >> 3, ch = task & 7;
            int cont = ch ^ (row & 7);
            g2lds16(Bbase + (size_t)(s0 + row) * 384 + k0 + cont * 8, Bt + task * 8);
        }
        __syncthreads();
        #pragma unroll
        for (int kk = 0; kk < 2; kk++) {
            b16x8 af[4], bf[4];
            #pragma unroll
            for (int mi = 0; mi < 4; mi++) {
                int r = wr * 64 + mi * 16 + li;
                af[mi] = *(const b16x8*)(At + r * 64 + (((kk * 4 + g) ^ (r & 7)) * 8));
            }
            #pragma unroll
            for (int nf = 0; nf < 4; nf++) {
                int r = wc * 64 + nf * 16 + li;
                bf[nf] = *(const b16x8*)(Bt + r * 64 + (((kk * 4 + g) ^ (r & 7)) * 8));
            }
            #pragma unroll
            for (int mi = 0; mi < 4; mi++)
                #pragma unroll
                for (int nf = 0; nf < 4; nf++)
                    acc[mi][nf] = __builtin_amdgcn_mfma_f32_16x16x32_bf16(af[mi], bf[nf], acc[mi][nf], 0, 0, 0);
        }
    }

    #pragma unroll
    for (int mi = 0; mi < 4; mi++) {
        #pragma unroll
        for (int nf = 0; nf < 4; nf++) {
            int o = o0 + wr * 64 + mi * 16 + g * 4;
            int s = s0 + wc * 64 + nf * 16 + li;
            #pragma unroll
            for (int j = 0; j < 4; j++)
                Yf[((size_t)b * CCH + o + j) * (size_t)NQ + s] = acc[mi][nf][j] + bias[o + j];
        }
    }
}

// ---------------------------------------------------------------------------
// Flash attention v9: counted-vmcnt pipeline (T3/T4).  3 LDS buffers, ONE
// raw s_barrier per tile, NEVER vmcnt(0) in the main loop.  Per wave the
// only in-loop VMEM is the stage loads — wave-uniform count (waves 0-1: 4,
// waves 2-3: 3) — so s_waitcnt vmcnt(N) waits exactly for tile tt while
// tile tt+1's loads stay in flight.  Writer targets buf (tt+2)%3; slowest
// reader is on tt%3 -> race-free with 1-tile skew.  Rest = round-13 compute.
// ---------------------------------------------------------------------------
__global__ __launch_bounds__(256, 2) void attn_kern(
    const short* __restrict__ qT, const short* __restrict__ kT,
    const short* __restrict__ vC, short* __restrict__ attT)
{
    __shared__ short Kl[3][6 * 64 * 8];   // [buf][d-chunk 0..5][row][8]
    __shared__ short Vl[3][8 * 64 * 8];   // [buf][key-chunk 0..7][d-row][8]
    const int wgid = blockIdx.x;
    const int nid = (wgid & 7) * 64 + (wgid >> 3);     // XCD swizzle (512 = 8*64)
    const int qt = nid & 15, hh = (nid >> 4) & 7, b = nid >> 7;
    const int t = threadIdx.x, wave = t >> 6, lane = t & 63;
    const int h = lane >> 5, c = lane & 31;
    const int n0 = qt * 256 + wave * 64;

    const short* qp = qT + (size_t)b * NQ * CCH + hh * HDIM;
    const short* kp = kT + (size_t)b * NK * CCH + hh * HDIM;
    const short* vp = vC + ((size_t)b * CCH + hh * HDIM) * NK;

    // init V pad rows 48..63 of all 3 buffers: row 48 = 1.0 (l-col), rest 0
    for (int i = t; i < 384; i += 256) {          // 3 bufs x 8 chunks x 16 rows
        int bufi = i >> 7, rem = i & 127;
        int ch = rem >> 4, row = 48 + (rem & 15);
        b16x8 val = {};
        if (row == 48)
            #pragma unroll
            for (int e = 0; e < 8; e++) val[e] = (short)0x3F80;
        *(b16x8*)(&Vl[bufi][(ch * 64 + row) * 8]) = val;
    }
    asm volatile("s_waitcnt lgkmcnt(0)" ::: "memory");  // pad writes retired

    // Q B-frags (persist): lane holds q = c (per qb), d = dc*16 + h*8 + e
    b16x8 qf[2][3];
    #pragma unroll
    for (int qb = 0; qb < 2; qb++)
        #pragma unroll
        for (int dc = 0; dc < 3; dc++)
            qf[qb][dc] = *(const b16x8*)(qp + (size_t)(n0 + qb * 32 + c) * CCH + dc * 16 + h * 8);
    asm volatile("s_waitcnt vmcnt(0)" ::: "memory");    // qf resident; clean counter

    // hoisted staging geometry (tile-invariant)
    const int rowS = t & 63;
    const int chA = t >> 6;                        // == wave, 0..3
    const int keyS = (rowS & 51) | ((rowS & 4) << 1) | ((rowS & 8) >> 1);
    const short* ksrcA = kp + (size_t)keyS * CCH + chA * 8;
    const bool  kvalB = (chA + 4) < 6;             // wave-uniform: waves 0,1
    const bool  vval  = rowS < 48;
    const short* vsrcA = vp + (size_t)rowS * NK + chA * 8;
    const int taskA8 = t * 8, taskB8 = (t + 256) * 8;

    auto stage = [&](int m0, int bi) {
        size_t koff = (size_t)m0 * CCH;
        g2lds16(ksrcA + koff, &Kl[bi][taskA8]);                    // 1 inst, all waves
        if (kvalB) g2lds16(ksrcA + koff + 32, &Kl[bi][taskB8]);    // +1, waves 0,1
        if (vval) {                                                // masked, still issued
            g2lds16(vsrcA + m0, &Vl[bi][taskA8]);                  // +1
            g2lds16(vsrcA + m0 + 32, &Vl[bi][taskB8]);             // +1
        }
    };

    f32x16 O[2][2] = {};       // [qb][dblock];  O[qb][1] col c=16 accumulates l

    stage(0, 0);
    stage(64, 1);
    int cur = 0;
    for (int tt = 0; tt < 16; ++tt) {
        // wait for tile tt's loads only (tt+1's stay in flight)
        if (tt < 15) {
            if (wave < 2) asm volatile("s_waitcnt vmcnt(4)" ::: "memory");
            else          asm volatile("s_waitcnt vmcnt(3)" ::: "memory");
        } else {
            asm volatile("s_waitcnt vmcnt(0)" ::: "memory");
        }
        __builtin_amdgcn_s_barrier();
        const short* Kb = Kl[cur];
        const short* Vb = Vl[cur];
        #pragma unroll
        for (int kb = 0; kb < 2; kb++) {
            b16x8 kf[3];
            #pragma unroll
            for (int dc = 0; dc < 3; dc++)
                kf[dc] = *(const b16x8*)(Kb + (((dc * 2 + h) * 64) + kb * 32 + c) * 8);
            f32x16 s0v = {}, s1v = {};
            __builtin_amdgcn_s_setprio(1);
            #pragma unroll
            for (int dc = 0; dc < 3; dc++) {
                s0v = __builtin_amdgcn_mfma_f32_32x32x16_bf16(kf[dc], qf[0][dc], s0v, 0, 0, 0);
                s1v = __builtin_amdgcn_mfma_f32_32x32x16_bf16(kf[dc], qf[1][dc], s1v, 0, 0, 0);
            }
            __builtin_amdgcn_s_setprio(0);
            b16x8 pfrag[2][2];
            #pragma unroll
            for (int qb = 0; qb < 2; qb++) {
                float p[16];
                #pragma unroll
                for (int r = 0; r < 16; r++)
                    p[r] = __builtin_amdgcn_exp2f(qb ? s1v[r] : s0v[r]);
                #pragma unroll
                for (int kk = 0; kk < 2; kk++) {
                    union { unsigned u[4]; b16x8 v; } w;
                    #pragma unroll
                    for (int wd = 0; wd < 4; wd++)
                        asm("v_cvt_pk_bf16_f32 %0, %1, %2"
                            : "=v"(w.u[wd])
                            : "v"(p[kk * 8 + wd * 2]), "v"(p[kk * 8 + wd * 2 + 1]));
                    pfrag[qb][kk] = w.v;
                }
            }
            __builtin_amdgcn_s_setprio(1);
            #pragma unroll
            for (int kk = 0; kk < 2; kk++)
                #pragma unroll
                for (int db = 0; db < 2; db++) {
                    b16x8 vf = *(const b16x8*)(Vb + (((kb * 4 + kk * 2 + h) * 64) + db * 32 + c) * 8);
                    #pragma unroll
                    for (int qb = 0; qb < 2; qb++)
                        O[qb][db] = __builtin_amdgcn_mfma_f32_32x32x16_bf16(pfrag[qb][kk], vf, O[qb][db], 0, 0, 0);
                }
            __builtin_amdgcn_s_setprio(0);
        }
        // prefetch tile tt+2 into buffer (cur+2)%3 (all waves past tt-1 reads)
        if (tt < 14) {
            int nb = cur + 2; if (nb >= 3) nb -= 3;
            stage((tt + 2) * 64, nb);
        }
        cur = (cur == 2) ? 0 : cur + 1;
    }

    __syncthreads();   // full drain: all waves done reading V before overlay
    // l[q-slot r] lives in lane (h, c=16) at O[qb][1][r]; wave-private bounce
    short* Olw = ((short*)Vl) + wave * 2048;   // 4 KB per wave
    #pragma unroll
    for (int qb = 0; qb < 2; qb++) {
        #pragma unroll
        for (int r = 0; r < 16; r++) {
            int qrow = (r & 3) + 8 * (r >> 2) + 4 * h;
            float lr = __shfl(O[qb][1][r], (lane & 32) | 16);
            float iq = 1.0f / lr;
            #pragma unroll
            for (int db = 0; db < 2; db++) {
                int d = db * 32 + c;
                if (d < 48)
                    Olw[qrow * 64 + (((d >> 3) ^ (qrow & 7)) * 8) + (d & 7)] =
                        (short)f2bf(O[qb][db][r] * iq);
            }
        }
        #pragma unroll
        for (int it = 0; it < 4; it++) {
            int idx = it * 64 + lane;
            int row = idx >> 3, c8 = idx & 7;
            if (c8 < 6) {
                b16x8 val = *(const b16x8*)(Olw + row * 64 + ((c8 ^ (row & 7)) * 8));
                *(b16x8*)(attT + ((size_t)b * NQ + n0 + qb * 32 + row) * CCH + hh * HDIM + c8 * 8) = val;
            }
        }
    }
}

// ---------------------------------------------------------------------------
extern "C" void kernel_launch(void* const* d_in, const int* in_sizes, int n_in,
                              void* d_out, int out_size, void* d_ws, size_t ws_size,
                              hipStream_t stream) {
    const float* x    = (const float*)d_in[0];
    const float* Wq   = (const float*)d_in[1];
    const float* Wk   = (const float*)d_in[2];
    const float* Wv   = (const float*)d_in[3];
    const float* Wsr  = (const float*)d_in[4];
    const float* bsr  = (const float*)d_in[5];
    const float* Wp   = (const float*)d_in[6];
    const float* bp   = (const float*)d_in[7];
    const float* relh = (const float*)d_in[8];
    const float* relw = (const float*)d_in[9];
    float* out = (float*)d_out;

    short* ws = (short*)d_ws;
    size_t off = 0;
    auto alloc = [&](size_t n) { short* p = ws + off; off += n; return p; };
    short* WqB  = alloc(147456);
    short* WkvB = alloc(294912);
    short* WsrB = alloc(589824);
    short* WpB  = alloc(147456);
    short* xT   = alloc((size_t)BATCH * NQ * CCH);
    short* xsrT = alloc((size_t)BATCH * NK * CCH);
    short* qTb  = alloc((size_t)BATCH * NQ * CCH);
    short* kTb  = alloc((size_t)BATCH * NK * CCH);
    short* vCb  = alloc((size_t)BATCH * CCH * NK);
    short* attT = alloc((size_t)BATCH * NQ * CCH);

    prep_kern<<<dim3(576, 6), 256, 0, stream>>>(Wq, Wk, Wv, Wsr, Wp, x,
                                                WqB, WkvB, WsrB, WpB, xT);
    fused_gemm1<<<dim3(120, 1, BATCH), 256, 0, stream>>>(WsrB, WqB, xT, bsr, xsrT, qTb);
    kv_gemm<<<dim3(8, 6, BATCH), 256, 0, stream>>>(WkvB, xsrT, relh, relw, kTb, vCb);
    attn_kern<<<dim3(512), 256, 0, stream>>>(qTb, kTb, vCb, attT);
    p_gemm<<<dim3(32, 3, BATCH), 256, 0, stream>>>(WpB, attT, out, bp);
}